// Round 1
// baseline (428.646 us; speedup 1.0000x reference)
//
#include <hip/hip_runtime.h>

typedef __bf16 bf16x8 __attribute__((ext_vector_type(8)));
typedef float f32x4 __attribute__((ext_vector_type(4)));

#define F_FIELDS 26
#define V_FIELD  8000
#define V_TOT    208000
#define D_EMBD   16
#define DNN_IN   10816   // 26*26*16
#define BS       4096
#define ND       13
#define H1_DIM   256
#define H2_DIM   128

__device__ __forceinline__ unsigned short f2bf(float f) {
  unsigned u = __float_as_uint(f);
  u += 0x7fffu + ((u >> 16) & 1u);      // round-to-nearest-even
  return (unsigned short)(u >> 16);
}
__device__ __forceinline__ float bf2f(unsigned short h) {
  return __uint_as_float(((unsigned)h) << 16);
}

__device__ __forceinline__ void gload16(const void* g, void* l) {
  __builtin_amdgcn_global_load_lds(
      (const __attribute__((address_space(1))) unsigned int*)g,
      (__attribute__((address_space(3))) unsigned int*)l, 16, 0, 0);
}

// ---------------- prep: fp32 -> bf16 weight conversion -----------------
__global__ void k_prep(const float* __restrict__ W1, const float* __restrict__ W2,
                       unsigned short* __restrict__ W1b, unsigned short* __restrict__ W2b) {
  const int n1 = H1_DIM * DNN_IN;
  const int n2 = H2_DIM * H1_DIM;
  for (int i = blockIdx.x * blockDim.x + threadIdx.x; i < n1 + n2;
       i += gridDim.x * blockDim.x) {
    if (i < n1) W1b[i] = f2bf(W1[i]);
    else        W2b[i - n1] = f2bf(W2[i - n1]);
  }
}

// ---------------- gather: A tensor + fm1 + fm2 -----------------
// block = one sample. A[b,i,j,:] = emb[i, X[b,j], :]; 676 rows of 16 floats.
__global__ __launch_bounds__(256) void k_gather(
    const int* __restrict__ Xs, const float* __restrict__ emb,
    const float* __restrict__ fm1_emb, const float* __restrict__ bias,
    const float* __restrict__ fm1dW, const float* __restrict__ fm1db,
    const float* __restrict__ Xd,
    unsigned short* __restrict__ Abf, float* __restrict__ fm12) {
  const int b = blockIdx.x;
  const int tid = threadIdx.x;
  const int lane = tid & 63, wave = tid >> 6;
  __shared__ int   sidx[F_FIELDS];
  __shared__ float sc1[F_FIELDS];
  __shared__ float As[676 * 17];       // stride 17 to spread LDS banks
  __shared__ float wred[4];

  if (tid < F_FIELDS) {
    int v = Xs[b * F_FIELDS + tid] + tid * V_FIELD;
    sidx[tid] = v;
    sc1[tid] = fm1_emb[v];
  }
  __syncthreads();

  const int q = tid & 3, rbase = tid >> 2;   // 4 lanes per row (float4 each)
  float4 vv[11];
#pragma unroll
  for (int it = 0; it < 11; ++it) {          // issue all loads first (MLP)
    int r = rbase + it * 64;
    if (r < 676) {
      int i = r / 26, j = r - i * 26;
      const float* src = emb + ((size_t)i * V_TOT + sidx[j]) * D_EMBD + q * 4;
      vv[it] = *(const float4*)src;
    }
  }
#pragma unroll
  for (int it = 0; it < 11; ++it) {
    int r = rbase + it * 64;
    if (r < 676) {
      float* dst = &As[r * 17 + q * 4];
      dst[0] = vv[it].x; dst[1] = vv[it].y; dst[2] = vv[it].z; dst[3] = vv[it].w;
      ushort4 u;
      u.x = f2bf(vv[it].x); u.y = f2bf(vv[it].y);
      u.z = f2bf(vv[it].z); u.w = f2bf(vv[it].w);
      *(ushort4*)&Abf[(size_t)b * DNN_IN + r * 16 + q * 4] = u;
    }
  }
  __syncthreads();

  // fm2 = sum_{i<j} dot(A[b,i,j,:], A[b,j,i,:]) ; 325 pairs
  float acc2 = 0.f;
  for (int p = tid; p < 325; p += 256) {
    float disc = sqrtf((float)(2601 - 8 * p));   // exact for these perfect squares
    int i = (int)((51.f - disc) * 0.5f);
    int cum = 25 * i - ((i * (i - 1)) >> 1);
    int j = i + 1 + (p - cum);
    const float* r1 = &As[(i * 26 + j) * 17];
    const float* r2 = &As[(j * 26 + i) * 17];
    float s = 0.f;
#pragma unroll
    for (int d = 0; d < 16; ++d) s += r1[d] * r2[d];
    acc2 += s;
  }
#pragma unroll
  for (int off = 32; off; off >>= 1) acc2 += __shfl_down(acc2, off);
  if (lane == 0) wred[wave] = acc2;
  __syncthreads();
  if (tid == 0) {
    float fm2 = wred[0] + wred[1] + wred[2] + wred[3];
    float f1 = bias[0] + fm1db[0];
#pragma unroll
    for (int j = 0; j < F_FIELDS; ++j) f1 += sc1[j];
    for (int k = 0; k < ND; ++k) f1 += Xd[b * ND + k] * fm1dW[k];
    fm12[b] = f1 + fm2;
  }
}

// ---------------- dense relu add (in-place bf16 RMW on Abf) -----------------
// block = (field i, 128-sample tile); dense_W slice 416x13 staged in LDS.
__global__ __launch_bounds__(256) void k_dense(
    const float* __restrict__ Xd, const float* __restrict__ dW,
    const float* __restrict__ db_, unsigned short* __restrict__ Dnn) {
  const int i = blockIdx.x;
  const int bb0 = blockIdx.y * 128;
  const int tid = threadIdx.x;
  __shared__ float sW[416 * 13];
  __shared__ float sb[416];
  __shared__ float sXd[128 * 13];
  for (int t = tid; t < 416 * 13; t += 256) sW[t] = dW[i * 416 * 13 + t];
  for (int t = tid; t < 416; t += 256)       sb[t] = db_[i * 416 + t];
  for (int t = tid; t < 128 * 13; t += 256)  sXd[t] = Xd[bb0 * ND + t];
  __syncthreads();
  for (int bb = 0; bb < 128; ++bb) {
    size_t base = (size_t)(bb0 + bb) * DNN_IN + i * 416;
    for (int e = tid; e < 416; e += 256) {
      float acc = sb[e];
#pragma unroll
      for (int k = 0; k < 13; ++k) acc += sW[e * 13 + k] * sXd[bb * 13 + k];
      acc = fmaxf(acc, 0.f);
      float a = bf2f(Dnn[base + e]);
      Dnn[base + e] = f2bf(a + acc);
    }
  }
}

// ---------------- bf16 NT GEMM (C = A * B^T), m97 structure -----------------
// A: [M][K] bf16, B: [N][K] bf16, C fp32 [M][ldc]; 128x128 tile, split-K via z.
__global__ __launch_bounds__(256) void k_gemm_nt(
    const unsigned short* __restrict__ A, const unsigned short* __restrict__ B,
    float* __restrict__ C, int K, int ldc, int tot_steps, size_t c_split) {
  __shared__ unsigned short sA[128 * 32];
  __shared__ unsigned short sB[128 * 32];
  const int tid = threadIdx.x;
  const int lane = tid & 63, wave = tid >> 6;
  const int m0 = blockIdx.y * 128, n0 = blockIdx.x * 128;
  const int p = blockIdx.z, np = gridDim.z;
  const int s0 = (tot_steps * p) / np, s1 = (tot_steps * (p + 1)) / np;
  C += (size_t)p * c_split;

  const int q = tid & 3, rr = tid >> 2;
  const unsigned short* gA0 = A + (size_t)(m0 + rr) * K + q * 8;
  const unsigned short* gA1 = gA0 + (size_t)64 * K;
  const unsigned short* gB0 = B + (size_t)(n0 + rr) * K + q * 8;
  const unsigned short* gB1 = gB0 + (size_t)64 * K;
  unsigned short* lA0 = sA + wave * 512;   // HW adds lane*16B
  unsigned short* lA1 = lA0 + 2048;
  unsigned short* lB0 = sB + wave * 512;
  unsigned short* lB1 = lB0 + 2048;

  const int wr = wave >> 1, wc = wave & 1;
  const int fr = lane & 15, fk = lane >> 4;
  const unsigned short* pA = sA + (wr * 64 + fr) * 32 + fk * 8;
  const unsigned short* pB = sB + (wc * 64 + fr) * 32 + fk * 8;

  f32x4 acc[4][4] = {};

  for (int ks = s0; ks < s1; ++ks) {
    const int ko = ks * 32;
    gload16(gA0 + ko, lA0);
    gload16(gA1 + ko, lA1);
    gload16(gB0 + ko, lB0);
    gload16(gB1 + ko, lB1);
    __syncthreads();
    bf16x8 av[4], bv[4];
#pragma unroll
    for (int mi = 0; mi < 4; ++mi) av[mi] = *(const bf16x8*)(pA + mi * 512);
#pragma unroll
    for (int ni = 0; ni < 4; ++ni) bv[ni] = *(const bf16x8*)(pB + ni * 512);
#pragma unroll
    for (int mi = 0; mi < 4; ++mi)
#pragma unroll
      for (int ni = 0; ni < 4; ++ni)
        acc[mi][ni] = __builtin_amdgcn_mfma_f32_16x16x32_bf16(
            av[mi], bv[ni], acc[mi][ni], 0, 0, 0);
    __syncthreads();
  }
#pragma unroll
  for (int mi = 0; mi < 4; ++mi)
#pragma unroll
    for (int ni = 0; ni < 4; ++ni)
#pragma unroll
      for (int r = 0; r < 4; ++r) {
        int row = m0 + wr * 64 + mi * 16 + fk * 4 + r;
        int col = n0 + wc * 64 + ni * 16 + fr;
        C[(size_t)row * ldc + col] = acc[mi][ni][r];
      }
}

// ---------------- BN stage 1: reduce split-K partials + column stats ----------
__global__ void k_stat1(const float* __restrict__ Yp, const float* __restrict__ b1,
                        float* __restrict__ Y1, float* __restrict__ ps,
                        float* __restrict__ pq) {
  const int g = blockIdx.x, n = threadIdx.x;   // 256 groups x 16 rows, 256 cols
  const size_t plane = (size_t)BS * H1_DIM;
  float s = 0.f, s2 = 0.f;
  for (int bb = 0; bb < 16; ++bb) {
    size_t o = (size_t)(g * 16 + bb) * H1_DIM + n;
    float y = Yp[o] + Yp[o + plane] + Yp[o + 2 * plane] + Yp[o + 3 * plane] + b1[n];
    Y1[o] = y; s += y; s2 += y * y;
  }
  ps[g * H1_DIM + n] = s; pq[g * H1_DIM + n] = s2;
}

__global__ void k_statb(const float* __restrict__ ps, const float* __restrict__ pq,
                        float* __restrict__ mean, float* __restrict__ rstd,
                        int ncols, int ngroups) {
  int n = threadIdx.x;
  if (n < ncols) {
    float s = 0.f, s2 = 0.f;
    for (int g = 0; g < ngroups; ++g) { s += ps[g * ncols + n]; s2 += pq[g * ncols + n]; }
    float m = s / (float)BS;
    float v = s2 / (float)BS - m * m;
    mean[n] = m; rstd[n] = rsqrtf(v + 1e-5f);
  }
}

__global__ void k_apply1(const float* __restrict__ Y1, const float* __restrict__ mean,
                         const float* __restrict__ rstd, const float* __restrict__ g1,
                         const float* __restrict__ be1, unsigned short* __restrict__ H1) {
  const int g = blockIdx.x, n = threadIdx.x;
  float m = mean[n], r = rstd[n], gg = g1[n], bb_ = be1[n];
  for (int bb = 0; bb < 16; ++bb) {
    size_t o = (size_t)(g * 16 + bb) * H1_DIM + n;
    float h = (Y1[o] - m) * r * gg + bb_;
    H1[o] = f2bf(fmaxf(h, 0.f));
  }
}

__global__ void k_stat2(const float* __restrict__ Y2, const float* __restrict__ b2,
                        float* __restrict__ ps, float* __restrict__ pq) {
  const int g = blockIdx.x, n = threadIdx.x;   // 256 groups x 16 rows, 128 cols
  float s = 0.f, s2 = 0.f;
  for (int bb = 0; bb < 16; ++bb) {
    float y = Y2[(size_t)(g * 16 + bb) * H2_DIM + n] + b2[n];
    s += y; s2 += y * y;
  }
  ps[g * H2_DIM + n] = s; pq[g * H2_DIM + n] = s2;
}

// ---------------- final: BN2 + relu + Wout dot + sigmoid(fm12 + out) --------
__global__ __launch_bounds__(256) void k_final(
    const float* __restrict__ Y2, const float* __restrict__ b2,
    const float* __restrict__ g2, const float* __restrict__ be2,
    const float* __restrict__ mean2, const float* __restrict__ rstd2,
    const float* __restrict__ Wout, const float* __restrict__ bout,
    const float* __restrict__ fm12, float* __restrict__ out) {
  const int tid = threadIdx.x, wave = tid >> 6, lane = tid & 63;
  const int b = blockIdx.x * 4 + wave;
  float acc = 0.f;
#pragma unroll
  for (int nn = 0; nn < 2; ++nn) {
    int n = lane + nn * 64;
    float y = Y2[(size_t)b * H2_DIM + n] + b2[n];
    float h = (y - mean2[n]) * rstd2[n] * g2[n] + be2[n];
    acc += fmaxf(h, 0.f) * Wout[n];
  }
#pragma unroll
  for (int off = 32; off; off >>= 1) acc += __shfl_down(acc, off);
  if (lane == 0) {
    float logit = fm12[b] + acc + bout[0];
    out[b] = 1.f / (1.f + expf(-logit));
  }
}

extern "C" void kernel_launch(void* const* d_in, const int* in_sizes, int n_in,
                              void* d_out, int out_size, void* d_ws, size_t ws_size,
                              hipStream_t stream) {
  const int*   Xs     = (const int*)d_in[0];
  const float* Xd     = (const float*)d_in[1];
  const float* fm1e   = (const float*)d_in[2];
  const float* bias   = (const float*)d_in[3];
  const float* fm1dW  = (const float*)d_in[4];
  const float* fm1db  = (const float*)d_in[5];
  const float* emb    = (const float*)d_in[6];
  const float* dW     = (const float*)d_in[7];
  const float* db_    = (const float*)d_in[8];
  const float* W1     = (const float*)d_in[9];
  const float* b1     = (const float*)d_in[10];
  const float* g1     = (const float*)d_in[11];
  const float* be1    = (const float*)d_in[12];
  const float* W2     = (const float*)d_in[13];
  const float* b2     = (const float*)d_in[14];
  const float* g2     = (const float*)d_in[15];
  const float* be2    = (const float*)d_in[16];
  const float* Wout   = (const float*)d_in[17];
  const float* bout   = (const float*)d_in[18];
  float* out = (float*)d_out;

  char* w = (char*)d_ws;
  unsigned short* Dnn = (unsigned short*)w; w += (size_t)BS * DNN_IN * 2;      // 88.6 MB
  unsigned short* W1b = (unsigned short*)w; w += (size_t)H1_DIM * DNN_IN * 2;  // 5.5 MB
  unsigned short* W2b = (unsigned short*)w; w += (size_t)H2_DIM * H1_DIM * 2;
  float* fm12 = (float*)w;  w += (size_t)BS * 4;
  float* Ypart = (float*)w; w += (size_t)4 * BS * H1_DIM * 4;                  // 16.8 MB
  float* Y1 = (float*)w;    w += (size_t)BS * H1_DIM * 4;
  unsigned short* H1 = (unsigned short*)w; w += (size_t)BS * H1_DIM * 2;
  float* ps1 = (float*)w;   w += 256 * H1_DIM * 4;
  float* pq1 = (float*)w;   w += 256 * H1_DIM * 4;
  float* mean1 = (float*)w; w += H1_DIM * 4;
  float* rstd1 = (float*)w; w += H1_DIM * 4;
  float* Y2 = (float*)w;    w += (size_t)BS * H2_DIM * 4;
  float* ps2 = (float*)w;   w += 256 * H2_DIM * 4;
  float* pq2 = (float*)w;   w += 256 * H2_DIM * 4;
  float* mean2 = (float*)w; w += H2_DIM * 4;
  float* rstd2 = (float*)w; w += H2_DIM * 4;

  k_prep<<<2048, 256, 0, stream>>>(W1, W2, W1b, W2b);
  k_gather<<<BS, 256, 0, stream>>>(Xs, emb, fm1e, bias, fm1dW, fm1db, Xd, Dnn, fm12);
  k_dense<<<dim3(26, 32), 256, 0, stream>>>(Xd, dW, db_, Dnn);
  k_gemm_nt<<<dim3(2, 32, 4), 256, 0, stream>>>(Dnn, W1b, Ypart, DNN_IN, H1_DIM,
                                                DNN_IN / 32, (size_t)BS * H1_DIM);
  k_stat1<<<256, 256, 0, stream>>>(Ypart, b1, Y1, ps1, pq1);
  k_statb<<<1, 256, 0, stream>>>(ps1, pq1, mean1, rstd1, H1_DIM, 256);
  k_apply1<<<256, 256, 0, stream>>>(Y1, mean1, rstd1, g1, be1, H1);
  k_gemm_nt<<<dim3(1, 32, 1), 256, 0, stream>>>(H1, W2b, Y2, H1_DIM, H2_DIM,
                                                H1_DIM / 32, 0);
  k_stat2<<<256, 128, 0, stream>>>(Y2, b2, ps2, pq2);
  k_statb<<<1, 128, 0, stream>>>(ps2, pq2, mean2, rstd2, H2_DIM, 256);
  k_final<<<BS / 4, 256, 0, stream>>>(Y2, b2, g2, be2, mean2, rstd2, Wout, bout,
                                      fm12, out);
}

// Round 3
// 275.759 us; speedup vs baseline: 1.5544x; 1.5544x over previous
//
#include <hip/hip_runtime.h>

typedef __bf16 bf16x8 __attribute__((ext_vector_type(8)));
typedef float f32x4 __attribute__((ext_vector_type(4)));

#define F_FIELDS 26
#define V_FIELD  8000
#define V_TOT    208000
#define D_EMBD   16
#define DNN_IN   10816   // 26*26*16
#define BS       4096
#define ND       13
#define H1_DIM   256
#define H2_DIM   128
#define NP1      8       // gemm1 split-K planes

__device__ __forceinline__ unsigned short f2bf(float f) {
  unsigned u = __float_as_uint(f);
  u += 0x7fffu + ((u >> 16) & 1u);      // round-to-nearest-even
  return (unsigned short)(u >> 16);
}
__device__ __forceinline__ float bf2f(unsigned short h) {
  return __uint_as_float(((unsigned)h) << 16);
}

__device__ __forceinline__ void gload16(const void* g, void* l) {
  __builtin_amdgcn_global_load_lds(
      (const __attribute__((address_space(1))) unsigned int*)g,
      (__attribute__((address_space(3))) unsigned int*)l, 16, 0, 0);
}

__device__ __forceinline__ float dot8bf(uint4 a, uint4 b) {
  const unsigned* pa = (const unsigned*)&a;
  const unsigned* pb = (const unsigned*)&b;
  float s = 0.f;
#pragma unroll
  for (int k = 0; k < 4; ++k) {
    float alo = __uint_as_float(pa[k] << 16);
    float ahi = __uint_as_float(pa[k] & 0xffff0000u);
    float blo = __uint_as_float(pb[k] << 16);
    float bhi = __uint_as_float(pb[k] & 0xffff0000u);
    s += alo * blo + ahi * bhi;
  }
  return s;
}

// ---------------- gather: A tensor + fm1 + fm2 + W-conversion ---------------
// block = one sample. A[b,i,j,:] = emb[i, X[b,j], :]; 676 rows of 16 floats.
__global__ __launch_bounds__(256) void k_gather(
    const int* __restrict__ Xs, const float* __restrict__ emb,
    const float* __restrict__ fm1_emb, const float* __restrict__ bias,
    const float* __restrict__ fm1dW, const float* __restrict__ fm1db,
    const float* __restrict__ Xd,
    const float* __restrict__ W1, const float* __restrict__ W2,
    unsigned short* __restrict__ W1b, unsigned short* __restrict__ W2b,
    unsigned short* __restrict__ Abf, float* __restrict__ fm12) {
  const int b = blockIdx.x;
  const int tid = threadIdx.x;
  const int lane = tid & 63, wave = tid >> 6;
  __shared__ int   sidx[F_FIELDS];
  __shared__ float sc1[F_FIELDS];
  __shared__ __align__(16) unsigned short As[676 * 24];  // bf16, stride 24
  __shared__ float wred[4];

  if (tid < F_FIELDS) {
    int v = Xs[b * F_FIELDS + tid] + tid * V_FIELD;
    sidx[tid] = v;
    sc1[tid] = fm1_emb[v];
  }
  __syncthreads();

  const int q = tid & 3, rbase = tid >> 2;   // 4 lanes per row (float4 each)
  float4 vv[11];
#pragma unroll
  for (int it = 0; it < 11; ++it) {          // issue all gathers first (MLP)
    int r = rbase + it * 64;
    if (r < 676) {
      int i = r / 26, j = r - i * 26;
      const float* src = emb + ((size_t)i * V_TOT + sidx[j]) * D_EMBD + q * 4;
      vv[it] = *(const float4*)src;
    }
  }
  // W1/W2 -> bf16 conversion: independent work overlapping gather latency
  const int n1 = H1_DIM * DNN_IN, n2 = H2_DIM * H1_DIM;
  for (int t = b * 256 + tid; t < n1 + n2; t += BS * 256) {
    if (t < n1) W1b[t] = f2bf(W1[t]);
    else        W2b[t - n1] = f2bf(W2[t - n1]);
  }
#pragma unroll
  for (int it = 0; it < 11; ++it) {
    int r = rbase + it * 64;
    if (r < 676) {
      ushort4 u;
      u.x = f2bf(vv[it].x); u.y = f2bf(vv[it].y);
      u.z = f2bf(vv[it].z); u.w = f2bf(vv[it].w);
      *(ushort4*)&As[r * 24 + q * 4] = u;
      *(ushort4*)&Abf[(size_t)b * DNN_IN + r * 16 + q * 4] = u;
    }
  }
  __syncthreads();

  // fm2 = sum_{i<j} dot(A[b,i,j,:], A[b,j,i,:]) ; 325 pairs (bf16 products)
  float acc2 = 0.f;
  for (int p = tid; p < 325; p += 256) {
    float disc = sqrtf((float)(2601 - 8 * p));   // exact for perfect squares
    int i = (int)((51.f - disc) * 0.5f);
    int cum = 25 * i - ((i * (i - 1)) >> 1);
    int j = i + 1 + (p - cum);
    const unsigned short* r1 = &As[(i * 26 + j) * 24];
    const unsigned short* r2 = &As[(j * 26 + i) * 24];
    acc2 += dot8bf(*(const uint4*)r1, *(const uint4*)r2);
    acc2 += dot8bf(*(const uint4*)(r1 + 8), *(const uint4*)(r2 + 8));
  }
#pragma unroll
  for (int off = 32; off; off >>= 1) acc2 += __shfl_down(acc2, off);
  if (lane == 0) wred[wave] = acc2;
  __syncthreads();
  if (tid == 0) {
    float fm2 = wred[0] + wred[1] + wred[2] + wred[3];
    float f1 = bias[0] + fm1db[0];
#pragma unroll
    for (int j = 0; j < F_FIELDS; ++j) f1 += sc1[j];
    for (int k = 0; k < ND; ++k) f1 += Xd[b * ND + k] * fm1dW[k];
    fm12[b] = f1 + fm2;
  }
}

// ---------------- dense relu add (in-place bf16 RMW on Abf) -----------------
// block = (field i, 64-sample tile); dense_W slice 416x13 staged in LDS.
__global__ __launch_bounds__(256) void k_dense(
    const float* __restrict__ Xd, const float* __restrict__ dW,
    const float* __restrict__ db_, unsigned short* __restrict__ Dnn) {
  const int i = blockIdx.x;
  const int bb0 = blockIdx.y * 64;
  const int tid = threadIdx.x;
  __shared__ float sW[416 * 13];
  __shared__ float sb[416];
  __shared__ float sXd[64 * 13];
  for (int t = tid; t < 416 * 13; t += 256) sW[t] = dW[i * 416 * 13 + t];
  for (int t = tid; t < 416; t += 256)      sb[t] = db_[i * 416 + t];
  for (int t = tid; t < 64 * 13; t += 256)  sXd[t] = Xd[bb0 * ND + t];
  __syncthreads();
  for (int bb = 0; bb < 64; ++bb) {
    size_t base = (size_t)(bb0 + bb) * DNN_IN + i * 416;
    for (int e = tid; e < 416; e += 256) {
      float acc = sb[e];
#pragma unroll
      for (int k = 0; k < 13; ++k) acc += sW[e * 13 + k] * sXd[bb * 13 + k];
      acc = fmaxf(acc, 0.f);
      float a = bf2f(Dnn[base + e]);
      Dnn[base + e] = f2bf(a + acc);
    }
  }
}

// ---------------- GEMM1: Ypart[p] = Dnn(128-tile) x W1b^T, 2-phase pipeline --
// tile 128M x 256N (full N), 512 threads (8 waves 2x4), z-split 8 via id&7
// so each XCD owns one K-slice -> its 692 KB B-slice stays L2-resident.
__global__ __launch_bounds__(512) void k_gemm1(
    const unsigned short* __restrict__ A, const unsigned short* __restrict__ B,
    float* __restrict__ C) {
  __shared__ __align__(16) unsigned short sA[2][128 * 32];
  __shared__ __align__(16) unsigned short sB[2][256 * 32];
  const int tid = threadIdx.x;
  const int lane = tid & 63, wave = tid >> 6;
  const int id = blockIdx.x;
  const int p = id & 7, mt = id >> 3;          // XCD(id)=id%8 -> z-plane per XCD
  const int m0 = mt * 128;
  const int s0 = (338 * p) >> 3, s1 = (338 * (p + 1)) >> 3;
  C += (size_t)p * ((size_t)BS * H1_DIM);

  const int q = tid & 3, rr = tid >> 2;        // rr 0..127
  const unsigned short* gA  = A + (size_t)(m0 + rr) * DNN_IN + q * 8;
  const unsigned short* gB0 = B + (size_t)rr * DNN_IN + q * 8;
  const unsigned short* gB1 = gB0 + (size_t)128 * DNN_IN;
  const int lo = wave * 512;                   // ushort offset of wave's chunk

  const int wr = wave >> 2, wc = wave & 3;
  const int fr = lane & 15, fk = lane >> 4;
  const int oA = (wr * 64 + fr) * 32 + fk * 8;
  const int oB = (wc * 64 + fr) * 32 + fk * 8;

  f32x4 acc[4][4] = {};

  {
    const int ko = s0 * 32;
    gload16(gA + ko, &sA[0][lo]);
    gload16(gB0 + ko, &sB[0][lo]);
    gload16(gB1 + ko, &sB[0][4096 + lo]);
  }
  for (int ks = s0; ks < s1; ++ks) {
    const int cur = (ks - s0) & 1;
    if (ks + 1 < s1) {
      const int ko = (ks + 1) * 32;
      gload16(gA + ko, &sA[cur ^ 1][lo]);
      gload16(gB0 + ko, &sB[cur ^ 1][lo]);
      gload16(gB1 + ko, &sB[cur ^ 1][4096 + lo]);
      asm volatile("s_waitcnt vmcnt(3)" ::: "memory");  // wait cur's 3 only
    } else {
      asm volatile("s_waitcnt vmcnt(0)" ::: "memory");
    }
    __builtin_amdgcn_sched_barrier(0);
    __builtin_amdgcn_s_barrier();              // cur buffer staged for all waves
    bf16x8 av[4], bv[4];
#pragma unroll
    for (int mi = 0; mi < 4; ++mi) av[mi] = *(const bf16x8*)&sA[cur][oA + mi * 512];
#pragma unroll
    for (int ni = 0; ni < 4; ++ni) bv[ni] = *(const bf16x8*)&sB[cur][oB + ni * 512];
    asm volatile("s_waitcnt lgkmcnt(0)" ::: "memory");
    __builtin_amdgcn_sched_barrier(0);
    __builtin_amdgcn_s_barrier();              // frags in regs -> next stage may overwrite
#pragma unroll
    for (int mi = 0; mi < 4; ++mi)
#pragma unroll
      for (int ni = 0; ni < 4; ++ni)
        acc[mi][ni] = __builtin_amdgcn_mfma_f32_16x16x32_bf16(
            av[mi], bv[ni], acc[mi][ni], 0, 0, 0);
  }
#pragma unroll
  for (int mi = 0; mi < 4; ++mi)
#pragma unroll
    for (int ni = 0; ni < 4; ++ni)
#pragma unroll
      for (int r = 0; r < 4; ++r) {
        int row = m0 + wr * 64 + mi * 16 + fk * 4 + r;
        int col = wc * 64 + ni * 16 + fr;
        C[(size_t)row * H1_DIM + col] = acc[mi][ni][r];
      }
}

// -------- stat1: reduce 8 planes + b1 -> Y1, per-group partial stats --------
__global__ __launch_bounds__(256) void k_stat1(
    const float* __restrict__ Yp, const float* __restrict__ b1,
    float* __restrict__ Y1, float* __restrict__ ps, float* __restrict__ pq) {
  const int g = blockIdx.x, n = threadIdx.x;   // 256 groups x 16 rows
  const size_t plane = (size_t)BS * H1_DIM;
  float s = 0.f, s2 = 0.f;
  float bn = b1[n];
  for (int bb = 0; bb < 16; ++bb) {
    size_t o = (size_t)(g * 16 + bb) * H1_DIM + n;
    float y = bn;
#pragma unroll
    for (int pp = 0; pp < NP1; ++pp) y += Yp[o + pp * plane];
    Y1[o] = y; s += y; s2 += y * y;
  }
  ps[g * H1_DIM + n] = s;
  pq[g * H1_DIM + n] = s2;
}

// ---- apply1: deterministic inline stats reduce + BN1 + relu -> H1 (bf16) ---
__global__ __launch_bounds__(256) void k_apply1(
    const float* __restrict__ Y1, const float* __restrict__ ps,
    const float* __restrict__ pq, const float* __restrict__ g1,
    const float* __restrict__ be1, unsigned short* __restrict__ H1b) {
  const int g = blockIdx.x, n = threadIdx.x;
  float s = 0.f, s2 = 0.f;
  for (int gg = 0; gg < 256; ++gg) {           // fixed order -> deterministic
    s += ps[gg * H1_DIM + n];
    s2 += pq[gg * H1_DIM + n];
  }
  float m = s * (1.f / BS);
  float v = s2 * (1.f / BS) - m * m;
  float r = rsqrtf(v + 1e-5f);
  float ga = g1[n], bb_ = be1[n];
  for (int bb = 0; bb < 16; ++bb) {
    size_t o = (size_t)(g * 16 + bb) * H1_DIM + n;
    float h = (Y1[o] - m) * r * ga + bb_;
    H1b[o] = f2bf(fmaxf(h, 0.f));
  }
}

// -------- GEMM2 (32 blocks) + bias + per-block partial column stats ---------
__global__ __launch_bounds__(256) void k_gemm2(
    const unsigned short* __restrict__ A, const unsigned short* __restrict__ B,
    const float* __restrict__ b2, float* __restrict__ Y2,
    float* __restrict__ ps, float* __restrict__ pq) {
  __shared__ __align__(16) unsigned short sA[2][128 * 32];
  __shared__ __align__(16) unsigned short sB[2][128 * 32];
  __shared__ float redS[8][H2_DIM];
  __shared__ float redQ[8][H2_DIM];
  const int tid = threadIdx.x;
  const int lane = tid & 63, wave = tid >> 6;
  const int m0 = blockIdx.x * 128;

  const int q = tid & 3, rr = tid >> 2;        // rr 0..63
  const unsigned short* gA0 = A + (size_t)(m0 + rr) * H1_DIM + q * 8;
  const unsigned short* gA1 = gA0 + (size_t)64 * H1_DIM;
  const unsigned short* gB0 = B + (size_t)rr * H1_DIM + q * 8;
  const unsigned short* gB1 = gB0 + (size_t)64 * H1_DIM;
  const int lo = wave * 512;

  const int wr = wave >> 1, wc = wave & 1;
  const int fr = lane & 15, fk = lane >> 4;
  const int oA = (wr * 64 + fr) * 32 + fk * 8;
  const int oB = (wc * 64 + fr) * 32 + fk * 8;

  f32x4 acc[4][4] = {};
  {
    gload16(gA0, &sA[0][lo]);
    gload16(gA1, &sA[0][2048 + lo]);
    gload16(gB0, &sB[0][lo]);
    gload16(gB1, &sB[0][2048 + lo]);
  }
  for (int ks = 0; ks < 8; ++ks) {
    const int cur = ks & 1;
    if (ks + 1 < 8) {
      const int ko = (ks + 1) * 32;
      gload16(gA0 + ko, &sA[cur ^ 1][lo]);
      gload16(gA1 + ko, &sA[cur ^ 1][2048 + lo]);
      gload16(gB0 + ko, &sB[cur ^ 1][lo]);
      gload16(gB1 + ko, &sB[cur ^ 1][2048 + lo]);
      asm volatile("s_waitcnt vmcnt(4)" ::: "memory");
    } else {
      asm volatile("s_waitcnt vmcnt(0)" ::: "memory");
    }
    __builtin_amdgcn_sched_barrier(0);
    __builtin_amdgcn_s_barrier();
    bf16x8 av[4], bv[4];
#pragma unroll
    for (int mi = 0; mi < 4; ++mi) av[mi] = *(const bf16x8*)&sA[cur][oA + mi * 512];
#pragma unroll
    for (int ni = 0; ni < 4; ++ni) bv[ni] = *(const bf16x8*)&sB[cur][oB + ni * 512];
    asm volatile("s_waitcnt lgkmcnt(0)" ::: "memory");
    __builtin_amdgcn_sched_barrier(0);
    __builtin_amdgcn_s_barrier();
#pragma unroll
    for (int mi = 0; mi < 4; ++mi)
#pragma unroll
      for (int ni = 0; ni < 4; ++ni)
        acc[mi][ni] = __builtin_amdgcn_mfma_f32_16x16x32_bf16(
            av[mi], bv[ni], acc[mi][ni], 0, 0, 0);
  }
  // epilogue: bias, store Y2, per-column partial stats over this block's rows
  float sc[4] = {0.f, 0.f, 0.f, 0.f}, sq[4] = {0.f, 0.f, 0.f, 0.f};
#pragma unroll
  for (int ni = 0; ni < 4; ++ni) {
    int col = wc * 64 + ni * 16 + fr;
    float bcol = b2[col];
#pragma unroll
    for (int mi = 0; mi < 4; ++mi)
#pragma unroll
      for (int r = 0; r < 4; ++r) {
        int row = m0 + wr * 64 + mi * 16 + fk * 4 + r;
        float y = acc[mi][ni][r] + bcol;
        Y2[(size_t)row * H2_DIM + col] = y;
        sc[ni] += y; sq[ni] += y * y;
      }
  }
  const int slot = wr * 4 + fk;
#pragma unroll
  for (int ni = 0; ni < 4; ++ni) {
    int col = wc * 64 + ni * 16 + fr;
    redS[slot][col] = sc[ni];
    redQ[slot][col] = sq[ni];
  }
  __syncthreads();
  if (tid < H2_DIM) {
    float s = 0.f, s2 = 0.f;
#pragma unroll
    for (int sl = 0; sl < 8; ++sl) { s += redS[sl][tid]; s2 += redQ[sl][tid]; }
    ps[blockIdx.x * H2_DIM + tid] = s;
    pq[blockIdx.x * H2_DIM + tid] = s2;
  }
}

// -- final: deterministic stats reduce + BN2 + relu + Wout dot + sigmoid -----
__global__ __launch_bounds__(256) void k_final(
    const float* __restrict__ Y2, const float* __restrict__ ps,
    const float* __restrict__ pq, const float* __restrict__ g2,
    const float* __restrict__ be2, const float* __restrict__ Wout,
    const float* __restrict__ bout, const float* __restrict__ fm12,
    float* __restrict__ out) {
  const int tid = threadIdx.x, wave = tid >> 6, lane = tid & 63;
  __shared__ float sm[H2_DIM], sr[H2_DIM], sg[H2_DIM], sbe[H2_DIM], sw[H2_DIM];
  if (tid < H2_DIM) {
    float s = 0.f, s2 = 0.f;
    for (int g = 0; g < 32; ++g) {             // fixed order -> deterministic
      s += ps[g * H2_DIM + tid];
      s2 += pq[g * H2_DIM + tid];
    }
    float m = s * (1.f / BS);
    float v = s2 * (1.f / BS) - m * m;
    sm[tid] = m; sr[tid] = rsqrtf(v + 1e-5f);
    sg[tid] = g2[tid]; sbe[tid] = be2[tid]; sw[tid] = Wout[tid];
  }
  __syncthreads();
  const float bo = bout[0];
  for (int ii = 0; ii < 16; ++ii) {
    int s = blockIdx.x * 64 + wave * 16 + ii;
    float acc = 0.f;
#pragma unroll
    for (int nn = 0; nn < 2; ++nn) {
      int n = lane + nn * 64;
      float y = Y2[(size_t)s * H2_DIM + n];
      float h = (y - sm[n]) * sr[n] * sg[n] + sbe[n];
      acc += fmaxf(h, 0.f) * sw[n];
    }
#pragma unroll
    for (int off = 32; off; off >>= 1) acc += __shfl_down(acc, off);
    if (lane == 0) {
      float logit = fm12[s] + acc + bo;
      out[s] = 1.f / (1.f + expf(-logit));
    }
  }
}

extern "C" void kernel_launch(void* const* d_in, const int* in_sizes, int n_in,
                              void* d_out, int out_size, void* d_ws, size_t ws_size,
                              hipStream_t stream) {
  const int*   Xs     = (const int*)d_in[0];
  const float* Xd     = (const float*)d_in[1];
  const float* fm1e   = (const float*)d_in[2];
  const float* bias   = (const float*)d_in[3];
  const float* fm1dW  = (const float*)d_in[4];
  const float* fm1db  = (const float*)d_in[5];
  const float* emb    = (const float*)d_in[6];
  const float* dW     = (const float*)d_in[7];
  const float* db_    = (const float*)d_in[8];
  const float* W1     = (const float*)d_in[9];
  const float* b1     = (const float*)d_in[10];
  const float* g1     = (const float*)d_in[11];
  const float* be1    = (const float*)d_in[12];
  const float* W2     = (const float*)d_in[13];
  const float* b2     = (const float*)d_in[14];
  const float* g2     = (const float*)d_in[15];
  const float* be2    = (const float*)d_in[16];
  const float* Wout   = (const float*)d_in[17];
  const float* bout   = (const float*)d_in[18];
  float* out = (float*)d_out;

  char* w = (char*)d_ws;
  unsigned short* Dnn = (unsigned short*)w; w += (size_t)BS * DNN_IN * 2;      // 88.6 MB
  unsigned short* W1b = (unsigned short*)w; w += (size_t)H1_DIM * DNN_IN * 2;  // 5.5 MB
  unsigned short* W2b = (unsigned short*)w; w += (size_t)H2_DIM * H1_DIM * 2;
  float* fm12 = (float*)w;  w += (size_t)BS * 4;
  float* Ypart = (float*)w; w += (size_t)NP1 * BS * H1_DIM * 4;                // 33.6 MB
  float* Y1 = (float*)w;    w += (size_t)BS * H1_DIM * 4;
  unsigned short* H1b = (unsigned short*)w; w += (size_t)BS * H1_DIM * 2;
  float* Y2 = (float*)w;    w += (size_t)BS * H2_DIM * 4;
  float* ps1 = (float*)w;   w += 256 * H1_DIM * 4;
  float* pq1 = (float*)w;   w += 256 * H1_DIM * 4;
  float* ps2 = (float*)w;   w += 32 * H2_DIM * 4;
  float* pq2 = (float*)w;   w += 32 * H2_DIM * 4;

  k_gather<<<BS, 256, 0, stream>>>(Xs, emb, fm1e, bias, fm1dW, fm1db, Xd,
                                   W1, W2, W1b, W2b, Dnn, fm12);
  k_dense<<<dim3(26, 64), 256, 0, stream>>>(Xd, dW, db_, Dnn);
  k_gemm1<<<32 * NP1, 512, 0, stream>>>(Dnn, W1b, Ypart);
  k_stat1<<<256, 256, 0, stream>>>(Ypart, b1, Y1, ps1, pq1);
  k_apply1<<<256, 256, 0, stream>>>(Y1, ps1, pq1, g1, be1, H1b);
  k_gemm2<<<32, 256, 0, stream>>>(H1b, W2b, b2, Y2, ps2, pq2);
  k_final<<<BS / 64, 256, 0, stream>>>(Y2, ps2, pq2, g2, be2, Wout, bout, fm12, out);
}

// Round 4
// 213.050 us; speedup vs baseline: 2.0119x; 1.2943x over previous
//
#include <hip/hip_runtime.h>

typedef __bf16 bf16x8 __attribute__((ext_vector_type(8)));
typedef float f32x4 __attribute__((ext_vector_type(4)));

#define F_FIELDS 26
#define V_FIELD  8000
#define V_TOT    208000
#define D_EMBD   16
#define DNN_IN   10816   // 26*26*16
#define BS       4096
#define ND       13
#define H1_DIM   256
#define H2_DIM   128
#define NP1      8       // gemm1 split-K planes

__device__ __forceinline__ unsigned short f2bf(float f) {
  unsigned u = __float_as_uint(f);
  u += 0x7fffu + ((u >> 16) & 1u);      // round-to-nearest-even
  return (unsigned short)(u >> 16);
}
__device__ __forceinline__ float bf2f(unsigned short h) {
  return __uint_as_float(((unsigned)h) << 16);
}
__device__ __forceinline__ float bflo(unsigned u) { return __uint_as_float(u << 16); }
__device__ __forceinline__ float bfhi(unsigned u) { return __uint_as_float(u & 0xffff0000u); }
__device__ __forceinline__ unsigned packbf(float a, float b) {
  return (unsigned)f2bf(a) | ((unsigned)f2bf(b) << 16);
}

__device__ __forceinline__ void gload16(const void* g, void* l) {
  __builtin_amdgcn_global_load_lds(
      (const __attribute__((address_space(1))) unsigned int*)g,
      (__attribute__((address_space(3))) unsigned int*)l, 16, 0, 0);
}

__device__ __forceinline__ float dot8bf(uint4 a, uint4 b) {
  const unsigned* pa = (const unsigned*)&a;
  const unsigned* pb = (const unsigned*)&b;
  float s = 0.f;
#pragma unroll
  for (int k = 0; k < 4; ++k)
    s += bflo(pa[k]) * bflo(pb[k]) + bfhi(pa[k]) * bfhi(pb[k]);
  return s;
}

// ---------------- gather: A tensor + fm1 + fm2 + W-conversion ---------------
// block = one sample. A[b,i,j,:] = emb[i, X[b,j], :]; 676 rows of 16 floats.
__global__ __launch_bounds__(256) void k_gather(
    const int* __restrict__ Xs, const float* __restrict__ emb,
    const float* __restrict__ fm1_emb, const float* __restrict__ bias,
    const float* __restrict__ fm1dW, const float* __restrict__ fm1db,
    const float* __restrict__ Xd,
    const float* __restrict__ W1, const float* __restrict__ W2,
    unsigned short* __restrict__ W1b, unsigned short* __restrict__ W2b,
    unsigned short* __restrict__ Abf, float* __restrict__ fm12) {
  const int b = blockIdx.x;
  const int tid = threadIdx.x;
  const int lane = tid & 63, wave = tid >> 6;
  __shared__ int   sidx[F_FIELDS];
  __shared__ float sc1[F_FIELDS];
  __shared__ __align__(16) unsigned short As[676 * 16];  // bf16, 21.6 KB
  __shared__ float wred[4];

  if (tid < F_FIELDS) {
    int v = Xs[b * F_FIELDS + tid] + tid * V_FIELD;
    sidx[tid] = v;
    sc1[tid] = fm1_emb[v];
  }
  __syncthreads();

  const int q = tid & 3, rbase = tid >> 2;   // 4 lanes per row (float4 each)
  float4 vv[11];
#pragma unroll
  for (int it = 0; it < 11; ++it) {          // issue all gathers first (MLP)
    int r = rbase + it * 64;
    if (r < 676) {
      int i = r / 26, j = r - i * 26;
      const float* src = emb + ((size_t)i * V_TOT + sidx[j]) * D_EMBD + q * 4;
      vv[it] = *(const float4*)src;
    }
  }
  // W1/W2 -> bf16 conversion: independent work overlapping gather latency
  const int n1 = H1_DIM * DNN_IN, n2 = H2_DIM * H1_DIM;
  for (int t = b * 256 + tid; t < n1 + n2; t += BS * 256) {
    if (t < n1) W1b[t] = f2bf(W1[t]);
    else        W2b[t - n1] = f2bf(W2[t - n1]);
  }
#pragma unroll
  for (int it = 0; it < 11; ++it) {
    int r = rbase + it * 64;
    if (r < 676) {
      ushort4 u;
      u.x = f2bf(vv[it].x); u.y = f2bf(vv[it].y);
      u.z = f2bf(vv[it].z); u.w = f2bf(vv[it].w);
      *(ushort4*)&As[r * 16 + q * 4] = u;
      *(ushort4*)&Abf[(size_t)b * DNN_IN + r * 16 + q * 4] = u;
    }
  }
  __syncthreads();

  // fm2 = sum_{i<j} dot(A[b,i,j,:], A[b,j,i,:]) ; 325 pairs (bf16 products)
  float acc2 = 0.f;
  for (int p = tid; p < 325; p += 256) {
    float disc = sqrtf((float)(2601 - 8 * p));   // exact for perfect squares
    int i = (int)((51.f - disc) * 0.5f);
    int cum = 25 * i - ((i * (i - 1)) >> 1);
    int j = i + 1 + (p - cum);
    const unsigned short* r1 = &As[(i * 26 + j) * 16];
    const unsigned short* r2 = &As[(j * 26 + i) * 16];
    acc2 += dot8bf(*(const uint4*)r1, *(const uint4*)r2);
    acc2 += dot8bf(*(const uint4*)(r1 + 8), *(const uint4*)(r2 + 8));
  }
#pragma unroll
  for (int off = 32; off; off >>= 1) acc2 += __shfl_down(acc2, off);
  if (lane == 0) wred[wave] = acc2;
  __syncthreads();
  if (tid == 0) {
    float fm2 = wred[0] + wred[1] + wred[2] + wred[3];
    float f1 = bias[0] + fm1db[0];
#pragma unroll
    for (int j = 0; j < F_FIELDS; ++j) f1 += sc1[j];
    for (int k = 0; k < ND; ++k) f1 += Xd[b * ND + k] * fm1dW[k];
    fm12[b] = f1 + fm2;
  }
}

// ------- dense relu add: register-resident weights, uint2 (8B) RMW ---------
// thread owns 4 consecutive elems (52 weight VGPRs); block = 1024 elems x 64
// samples; Xd broadcast from LDS. Pure HBM-bound (~177 MB RMW).
__global__ __launch_bounds__(256) void k_dense(
    const float* __restrict__ Xd, const float* __restrict__ dW,
    const float* __restrict__ db_, unsigned short* __restrict__ Dnn) {
  const int t = threadIdx.x;
  const int eg = blockIdx.x * 256 + t;       // uint2 group (4 elems)
  const int y0 = blockIdx.y * 64;
  __shared__ float sXd[64 * 13];
  for (int i = t; i < 64 * 13; i += 256) sXd[i] = Xd[y0 * 13 + i];
  __syncthreads();
  if (eg >= DNN_IN / 4) return;
  const int e = eg * 4;
  float wrg[4][13], brg[4];
#pragma unroll
  for (int j = 0; j < 4; ++j) {
    brg[j] = db_[e + j];
#pragma unroll
    for (int k = 0; k < 13; ++k) wrg[j][k] = dW[(e + j) * 13 + k];
  }
  uint2* dp = (uint2*)Dnn;
  for (int s0 = 0; s0 < 64; s0 += 8) {
    uint2 v[8];
#pragma unroll
    for (int u = 0; u < 8; ++u)
      v[u] = dp[(size_t)(y0 + s0 + u) * (DNN_IN / 4) + eg];
#pragma unroll
    for (int u = 0; u < 8; ++u) {
      const float* xr = &sXd[(s0 + u) * 13];
      float d0 = brg[0], d1 = brg[1], d2 = brg[2], d3 = brg[3];
#pragma unroll
      for (int k = 0; k < 13; ++k) {
        float xk = xr[k];
        d0 += wrg[0][k] * xk; d1 += wrg[1][k] * xk;
        d2 += wrg[2][k] * xk; d3 += wrg[3][k] * xk;
      }
      float a0 = bflo(v[u].x) + fmaxf(d0, 0.f);
      float a1 = bfhi(v[u].x) + fmaxf(d1, 0.f);
      float a2 = bflo(v[u].y) + fmaxf(d2, 0.f);
      float a3 = bfhi(v[u].y) + fmaxf(d3, 0.f);
      uint2 o; o.x = packbf(a0, a1); o.y = packbf(a2, a3);
      dp[(size_t)(y0 + s0 + u) * (DNN_IN / 4) + eg] = o;
    }
  }
}

// -------- GEMM1: 64x256 tile, 3-buffer depth-2 pipeline, split-K 8 ----------
// grid 512 (= 64 mt x 8 planes, plane = id&7 -> one K-slice per XCD, B-slice
// L2-resident). 2 blocks/CU so barrier stalls decouple. vmcnt(10) counted:
// 5 loads/step/thread, 2 steps in flight.
__global__ __launch_bounds__(256) void k_gemm1(
    const unsigned short* __restrict__ A, const unsigned short* __restrict__ B,
    float* __restrict__ C) {
  __shared__ __align__(16) unsigned short sA[3][64 * 32];    // 12 KB
  __shared__ __align__(16) unsigned short sB[3][256 * 32];   // 48 KB
  const int tid = threadIdx.x;
  const int lane = tid & 63, w = tid >> 6;
  const int id = blockIdx.x;
  const int p = id & 7, mt = id >> 3;
  const int m0 = mt * 64;
  const int s0 = (338 * p) >> 3, s1 = (338 * (p + 1)) >> 3;
  C += (size_t)p * ((size_t)BS * H1_DIM);

  const int q = tid & 3, rr = tid >> 2;       // rr 0..63
  const unsigned short* gA  = A + (size_t)(m0 + rr) * DNN_IN + q * 8;
  const unsigned short* gB0 = B + (size_t)rr * DNN_IN + q * 8;
  const int fr = lane & 15, fk = lane >> 4;
  const int oA = fr * 32 + fk * 8;
  const int oB = (w * 64 + fr) * 32 + fk * 8;

  f32x4 acc[4][4] = {};

#define STAGE1(ks, bi) do { const int ko_ = (ks) * 32;                      \
    gload16(gA + ko_, &sA[bi][tid * 8]);                                    \
    gload16(gB0 + ko_, &sB[bi][tid * 8]);                                   \
    gload16(gB0 + (size_t)64 * DNN_IN + ko_, &sB[bi][2048 + tid * 8]);      \
    gload16(gB0 + (size_t)128 * DNN_IN + ko_, &sB[bi][4096 + tid * 8]);     \
    gload16(gB0 + (size_t)192 * DNN_IN + ko_, &sB[bi][6144 + tid * 8]); } while (0)

  STAGE1(s0, 0);
  if (s0 + 1 < s1) STAGE1(s0 + 1, 1);
  if (s0 + 2 < s1) STAGE1(s0 + 2, 2);

  int bi = 0;
  for (int ks = s0; ks < s1; ++ks) {
    if (ks + 2 < s1)      asm volatile("s_waitcnt vmcnt(10)" ::: "memory");
    else if (ks + 1 < s1) asm volatile("s_waitcnt vmcnt(5)" ::: "memory");
    else                  asm volatile("s_waitcnt vmcnt(0)" ::: "memory");
    __builtin_amdgcn_sched_barrier(0);
    __builtin_amdgcn_s_barrier();             // buf bi staged for all waves
    bf16x8 av[4], bv[4];
#pragma unroll
    for (int mi = 0; mi < 4; ++mi) av[mi] = *(const bf16x8*)&sA[bi][oA + mi * 512];
#pragma unroll
    for (int ni = 0; ni < 4; ++ni) bv[ni] = *(const bf16x8*)&sB[bi][oB + ni * 512];
    asm volatile("s_waitcnt lgkmcnt(0)" ::: "memory");
    __builtin_amdgcn_sched_barrier(0);
    __builtin_amdgcn_s_barrier();             // frags in regs -> buf reusable
    if (ks + 3 < s1) STAGE1(ks + 3, bi);
#pragma unroll
    for (int mi = 0; mi < 4; ++mi)
#pragma unroll
      for (int ni = 0; ni < 4; ++ni)
        acc[mi][ni] = __builtin_amdgcn_mfma_f32_16x16x32_bf16(
            av[mi], bv[ni], acc[mi][ni], 0, 0, 0);
    bi = bi + 1; if (bi == 3) bi = 0;
  }
#pragma unroll
  for (int mi = 0; mi < 4; ++mi)
#pragma unroll
    for (int ni = 0; ni < 4; ++ni)
#pragma unroll
      for (int r = 0; r < 4; ++r) {
        int row = m0 + mi * 16 + fk * 4 + r;
        int col = w * 64 + ni * 16 + fr;
        C[(size_t)row * H1_DIM + col] = acc[mi][ni][r];
      }
#undef STAGE1
}

// -------- stat1: reduce 8 planes + b1 -> Y1, per-group partial stats --------
__global__ __launch_bounds__(256) void k_stat1(
    const float* __restrict__ Yp, const float* __restrict__ b1,
    float* __restrict__ Y1, float* __restrict__ ps, float* __restrict__ pq) {
  const int g = blockIdx.x, n = threadIdx.x;   // 256 groups x 16 rows
  const size_t plane = (size_t)BS * H1_DIM;
  float s = 0.f, s2 = 0.f;
  float bn = b1[n];
  for (int bb = 0; bb < 16; ++bb) {
    size_t o = (size_t)(g * 16 + bb) * H1_DIM + n;
    float y = bn;
#pragma unroll
    for (int pp = 0; pp < NP1; ++pp) y += Yp[o + pp * plane];
    Y1[o] = y; s += y; s2 += y * y;
  }
  ps[g * H1_DIM + n] = s;
  pq[g * H1_DIM + n] = s2;
}

// ---- apply1: deterministic inline stats reduce + BN1 + relu -> H1 (bf16) ---
__global__ __launch_bounds__(256) void k_apply1(
    const float* __restrict__ Y1, const float* __restrict__ ps,
    const float* __restrict__ pq, const float* __restrict__ g1,
    const float* __restrict__ be1, unsigned short* __restrict__ H1b) {
  const int g = blockIdx.x, n = threadIdx.x;
  float s = 0.f, s2 = 0.f;
  for (int gg = 0; gg < 256; ++gg) {           // fixed order -> deterministic
    s += ps[gg * H1_DIM + n];
    s2 += pq[gg * H1_DIM + n];
  }
  float m = s * (1.f / BS);
  float v = s2 * (1.f / BS) - m * m;
  float r = rsqrtf(v + 1e-5f);
  float ga = g1[n], bb_ = be1[n];
  for (int bb = 0; bb < 16; ++bb) {
    size_t o = (size_t)(g * 16 + bb) * H1_DIM + n;
    float h = (Y1[o] - m) * r * ga + bb_;
    H1b[o] = f2bf(fmaxf(h, 0.f));
  }
}

// -------- GEMM2 (32 blocks) + bias + per-block partial column stats ---------
__global__ __launch_bounds__(256) void k_gemm2(
    const unsigned short* __restrict__ A, const unsigned short* __restrict__ B,
    const float* __restrict__ b2, float* __restrict__ Y2,
    float* __restrict__ ps, float* __restrict__ pq) {
  __shared__ __align__(16) unsigned short sA[2][128 * 32];
  __shared__ __align__(16) unsigned short sB[2][128 * 32];
  __shared__ float redS[8][H2_DIM];
  __shared__ float redQ[8][H2_DIM];
  const int tid = threadIdx.x;
  const int lane = tid & 63, wave = tid >> 6;
  const int m0 = blockIdx.x * 128;

  const int q = tid & 3, rr = tid >> 2;        // rr 0..63
  const unsigned short* gA0 = A + (size_t)(m0 + rr) * H1_DIM + q * 8;
  const unsigned short* gA1 = gA0 + (size_t)64 * H1_DIM;
  const unsigned short* gB0 = B + (size_t)rr * H1_DIM + q * 8;
  const unsigned short* gB1 = gB0 + (size_t)64 * H1_DIM;
  const int lo = wave * 512;

  const int wr = wave >> 1, wc = wave & 1;
  const int fr = lane & 15, fk = lane >> 4;
  const int oA = (wr * 64 + fr) * 32 + fk * 8;
  const int oB = (wc * 64 + fr) * 32 + fk * 8;

  f32x4 acc[4][4] = {};
  {
    gload16(gA0, &sA[0][lo]);
    gload16(gA1, &sA[0][2048 + lo]);
    gload16(gB0, &sB[0][lo]);
    gload16(gB1, &sB[0][2048 + lo]);
  }
  for (int ks = 0; ks < 8; ++ks) {
    const int cur = ks & 1;
    if (ks + 1 < 8) {
      const int ko = (ks + 1) * 32;
      gload16(gA0 + ko, &sA[cur ^ 1][lo]);
      gload16(gA1 + ko, &sA[cur ^ 1][2048 + lo]);
      gload16(gB0 + ko, &sB[cur ^ 1][lo]);
      gload16(gB1 + ko, &sB[cur ^ 1][2048 + lo]);
      asm volatile("s_waitcnt vmcnt(4)" ::: "memory");
    } else {
      asm volatile("s_waitcnt vmcnt(0)" ::: "memory");
    }
    __builtin_amdgcn_sched_barrier(0);
    __builtin_amdgcn_s_barrier();
    bf16x8 av[4], bv[4];
#pragma unroll
    for (int mi = 0; mi < 4; ++mi) av[mi] = *(const bf16x8*)&sA[cur][oA + mi * 512];
#pragma unroll
    for (int ni = 0; ni < 4; ++ni) bv[ni] = *(const bf16x8*)&sB[cur][oB + ni * 512];
    asm volatile("s_waitcnt lgkmcnt(0)" ::: "memory");
    __builtin_amdgcn_sched_barrier(0);
    __builtin_amdgcn_s_barrier();
#pragma unroll
    for (int mi = 0; mi < 4; ++mi)
#pragma unroll
      for (int ni = 0; ni < 4; ++ni)
        acc[mi][ni] = __builtin_amdgcn_mfma_f32_16x16x32_bf16(
            av[mi], bv[ni], acc[mi][ni], 0, 0, 0);
  }
  // epilogue: bias, store Y2, per-column partial stats over this block's rows
  float sc[4] = {0.f, 0.f, 0.f, 0.f}, sq[4] = {0.f, 0.f, 0.f, 0.f};
#pragma unroll
  for (int ni = 0; ni < 4; ++ni) {
    int col = wc * 64 + ni * 16 + fr;
    float bcol = b2[col];
#pragma unroll
    for (int mi = 0; mi < 4; ++mi)
#pragma unroll
      for (int r = 0; r < 4; ++r) {
        int row = m0 + wr * 64 + mi * 16 + fk * 4 + r;
        float y = acc[mi][ni][r] + bcol;
        Y2[(size_t)row * H2_DIM + col] = y;
        sc[ni] += y; sq[ni] += y * y;
      }
  }
  const int slot = wr * 4 + fk;
#pragma unroll
  for (int ni = 0; ni < 4; ++ni) {
    int col = wc * 64 + ni * 16 + fr;
    redS[slot][col] = sc[ni];
    redQ[slot][col] = sq[ni];
  }
  __syncthreads();
  if (tid < H2_DIM) {
    float s = 0.f, s2 = 0.f;
#pragma unroll
    for (int sl = 0; sl < 8; ++sl) { s += redS[sl][tid]; s2 += redQ[sl][tid]; }
    ps[blockIdx.x * H2_DIM + tid] = s;
    pq[blockIdx.x * H2_DIM + tid] = s2;
  }
}

// -- final: deterministic stats reduce + BN2 + relu + Wout dot + sigmoid -----
__global__ __launch_bounds__(256) void k_final(
    const float* __restrict__ Y2, const float* __restrict__ ps,
    const float* __restrict__ pq, const float* __restrict__ g2,
    const float* __restrict__ be2, const float* __restrict__ Wout,
    const float* __restrict__ bout, const float* __restrict__ fm12,
    float* __restrict__ out) {
  const int tid = threadIdx.x, wave = tid >> 6, lane = tid & 63;
  __shared__ float sm[H2_DIM], sr[H2_DIM], sg[H2_DIM], sbe[H2_DIM], sw[H2_DIM];
  if (tid < H2_DIM) {
    float s = 0.f, s2 = 0.f;
    for (int g = 0; g < 32; ++g) {             // fixed order -> deterministic
      s += ps[g * H2_DIM + tid];
      s2 += pq[g * H2_DIM + tid];
    }
    float m = s * (1.f / BS);
    float v = s2 * (1.f / BS) - m * m;
    sm[tid] = m; sr[tid] = rsqrtf(v + 1e-5f);
    sg[tid] = g2[tid]; sbe[tid] = be2[tid]; sw[tid] = Wout[tid];
  }
  __syncthreads();
  const float bo = bout[0];
  for (int ii = 0; ii < 16; ++ii) {
    int s = blockIdx.x * 64 + wave * 16 + ii;
    float acc = 0.f;
#pragma unroll
    for (int nn = 0; nn < 2; ++nn) {
      int n = lane + nn * 64;
      float y = Y2[(size_t)s * H2_DIM + n];
      float h = (y - sm[n]) * sr[n] * sg[n] + sbe[n];
      acc += fmaxf(h, 0.f) * sw[n];
    }
#pragma unroll
    for (int off = 32; off; off >>= 1) acc += __shfl_down(acc, off);
    if (lane == 0) {
      float logit = fm12[s] + acc + bo;
      out[s] = 1.f / (1.f + expf(-logit));
    }
  }
}

extern "C" void kernel_launch(void* const* d_in, const int* in_sizes, int n_in,
                              void* d_out, int out_size, void* d_ws, size_t ws_size,
                              hipStream_t stream) {
  const int*   Xs     = (const int*)d_in[0];
  const float* Xd     = (const float*)d_in[1];
  const float* fm1e   = (const float*)d_in[2];
  const float* bias   = (const float*)d_in[3];
  const float* fm1dW  = (const float*)d_in[4];
  const float* fm1db  = (const float*)d_in[5];
  const float* emb    = (const float*)d_in[6];
  const float* dW     = (const float*)d_in[7];
  const float* db_    = (const float*)d_in[8];
  const float* W1     = (const float*)d_in[9];
  const float* b1     = (const float*)d_in[10];
  const float* g1     = (const float*)d_in[11];
  const float* be1    = (const float*)d_in[12];
  const float* W2     = (const float*)d_in[13];
  const float* b2     = (const float*)d_in[14];
  const float* g2     = (const float*)d_in[15];
  const float* be2    = (const float*)d_in[16];
  const float* Wout   = (const float*)d_in[17];
  const float* bout   = (const float*)d_in[18];
  float* out = (float*)d_out;

  char* w = (char*)d_ws;
  unsigned short* Dnn = (unsigned short*)w; w += (size_t)BS * DNN_IN * 2;      // 88.6 MB
  unsigned short* W1b = (unsigned short*)w; w += (size_t)H1_DIM * DNN_IN * 2;  // 5.5 MB
  unsigned short* W2b = (unsigned short*)w; w += (size_t)H2_DIM * H1_DIM * 2;
  float* fm12 = (float*)w;  w += (size_t)BS * 4;
  float* Ypart = (float*)w; w += (size_t)NP1 * BS * H1_DIM * 4;                // 33.6 MB
  float* Y1 = (float*)w;    w += (size_t)BS * H1_DIM * 4;
  unsigned short* H1b = (unsigned short*)w; w += (size_t)BS * H1_DIM * 2;
  float* Y2 = (float*)w;    w += (size_t)BS * H2_DIM * 4;
  float* ps1 = (float*)w;   w += 256 * H1_DIM * 4;
  float* pq1 = (float*)w;   w += 256 * H1_DIM * 4;
  float* ps2 = (float*)w;   w += 32 * H2_DIM * 4;
  float* pq2 = (float*)w;   w += 32 * H2_DIM * 4;

  k_gather<<<BS, 256, 0, stream>>>(Xs, emb, fm1e, bias, fm1dW, fm1db, Xd,
                                   W1, W2, W1b, W2b, Dnn, fm12);
  k_dense<<<dim3(11, 64), 256, 0, stream>>>(Xd, dW, db_, Dnn);
  k_gemm1<<<64 * NP1, 256, 0, stream>>>(Dnn, W1b, Ypart);
  k_stat1<<<256, 256, 0, stream>>>(Ypart, b1, Y1, ps1, pq1);
  k_apply1<<<256, 256, 0, stream>>>(Y1, ps1, pq1, g1, be1, H1b);
  k_gemm2<<<32, 256, 0, stream>>>(H1b, W2b, b2, Y2, ps2, pq2);
  k_final<<<BS / 64, 256, 0, stream>>>(Y2, ps2, pq2, g2, be2, Wout, bout, fm12, out);
}

// Round 6
// 187.130 us; speedup vs baseline: 2.2906x; 1.1385x over previous
//
#include <hip/hip_runtime.h>

typedef __bf16 bf16x8 __attribute__((ext_vector_type(8)));
typedef float f32x4 __attribute__((ext_vector_type(4)));

#define F_FIELDS 26
#define V_FIELD  8000
#define V_TOT    208000
#define D_EMBD   16
#define DNN_IN   10816   // 26*26*16
#define BS       4096
#define ND       13
#define H1_DIM   256
#define H2_DIM   128
#define NP1      8       // gemm1 split-K planes

__device__ __forceinline__ unsigned short f2bf(float f) {
  unsigned u = __float_as_uint(f);
  u += 0x7fffu + ((u >> 16) & 1u);      // round-to-nearest-even
  return (unsigned short)(u >> 16);
}
__device__ __forceinline__ float bf2f(unsigned short h) {
  return __uint_as_float(((unsigned)h) << 16);
}
__device__ __forceinline__ float bflo(unsigned u) { return __uint_as_float(u << 16); }
__device__ __forceinline__ float bfhi(unsigned u) { return __uint_as_float(u & 0xffff0000u); }

__device__ __forceinline__ void gload16(const void* g, void* l) {
  __builtin_amdgcn_global_load_lds(
      (const __attribute__((address_space(1))) unsigned int*)g,
      (__attribute__((address_space(3))) unsigned int*)l, 16, 0, 0);
}

__device__ __forceinline__ float dot8bf(uint4 a, uint4 b) {
  const unsigned* pa = (const unsigned*)&a;
  const unsigned* pb = (const unsigned*)&b;
  float s = 0.f;
#pragma unroll
  for (int k = 0; k < 4; ++k)
    s += bflo(pa[k]) * bflo(pb[k]) + bfhi(pa[k]) * bfhi(pb[k]);
  return s;
}

// ------- gather: A tensor + fm1 + fm2 + W1/W2/dense-W bf16 conversion -------
// block = one sample. A[b,i,j,:] = emb[i, X[b,j], :]; 676 rows of 16 floats.
__global__ __launch_bounds__(256) void k_gather(
    const int* __restrict__ Xs, const float* __restrict__ emb,
    const float* __restrict__ fm1_emb, const float* __restrict__ bias,
    const float* __restrict__ fm1dW, const float* __restrict__ fm1db,
    const float* __restrict__ Xd,
    const float* __restrict__ W1, const float* __restrict__ W2,
    const float* __restrict__ dW, const float* __restrict__ db_,
    unsigned short* __restrict__ W1b, unsigned short* __restrict__ W2b,
    unsigned short* __restrict__ dWb,
    unsigned short* __restrict__ Abf, float* __restrict__ fm12) {
  const int b = blockIdx.x;
  const int tid = threadIdx.x;
  const int lane = tid & 63, wave = tid >> 6;
  __shared__ int   sidx[F_FIELDS];
  __shared__ float sc1[F_FIELDS];
  __shared__ __align__(16) unsigned short As[676 * 16];  // bf16, 21.6 KB
  __shared__ float wred[4];

  if (tid < F_FIELDS) {
    int v = Xs[b * F_FIELDS + tid] + tid * V_FIELD;
    sidx[tid] = v;
    sc1[tid] = fm1_emb[v];
  }
  __syncthreads();

  const int q = tid & 3, rbase = tid >> 2;   // 4 lanes per row (float4 each)
  float4 vv[11];
#pragma unroll
  for (int it = 0; it < 11; ++it) {          // issue all gathers first (MLP)
    int r = rbase + it * 64;
    if (r < 676) {
      int i = r / 26, j = r - i * 26;
      const float* src = emb + ((size_t)i * V_TOT + sidx[j]) * D_EMBD + q * 4;
      vv[it] = *(const float4*)src;
    }
  }
  // W1/W2 -> bf16 conversion: independent work overlapping gather latency
  const int n1 = H1_DIM * DNN_IN, n2 = H2_DIM * H1_DIM;
  for (int t = b * 256 + tid; t < n1 + n2; t += BS * 256) {
    if (t < n1) W1b[t] = f2bf(W1[t]);
    else        W2b[t - n1] = f2bf(W2[t - n1]);
  }
  // dense-W augmented bf16 table (K=32): [0..12]=w, [13]=db, [14..31]=0
  for (int e = b * 256 + tid; e < DNN_IN; e += BS * 256) {
    unsigned short row[32];
#pragma unroll
    for (int k = 0; k < 13; ++k) row[k] = f2bf(dW[e * 13 + k]);
    row[13] = f2bf(db_[e]);
#pragma unroll
    for (int k = 14; k < 32; ++k) row[k] = 0;
#pragma unroll
    for (int k = 0; k < 32; ++k) dWb[e * 32 + k] = row[k];
  }
#pragma unroll
  for (int it = 0; it < 11; ++it) {
    int r = rbase + it * 64;
    if (r < 676) {
      ushort4 u;
      u.x = f2bf(vv[it].x); u.y = f2bf(vv[it].y);
      u.z = f2bf(vv[it].z); u.w = f2bf(vv[it].w);
      *(ushort4*)&As[r * 16 + q * 4] = u;
      *(ushort4*)&Abf[(size_t)b * DNN_IN + r * 16 + q * 4] = u;
    }
  }
  __syncthreads();

  // fm2 = sum_{i<j} dot(A[b,i,j,:], A[b,j,i,:]) ; 325 pairs (bf16 products)
  float acc2 = 0.f;
  for (int p = tid; p < 325; p += 256) {
    float disc = sqrtf((float)(2601 - 8 * p));   // exact for perfect squares
    int i = (int)((51.f - disc) * 0.5f);
    int cum = 25 * i - ((i * (i - 1)) >> 1);
    int j = i + 1 + (p - cum);
    const unsigned short* r1 = &As[(i * 26 + j) * 16];
    const unsigned short* r2 = &As[(j * 26 + i) * 16];
    acc2 += dot8bf(*(const uint4*)r1, *(const uint4*)r2);
    acc2 += dot8bf(*(const uint4*)(r1 + 8), *(const uint4*)(r2 + 8));
  }
#pragma unroll
  for (int off = 32; off; off >>= 1) acc2 += __shfl_down(acc2, off);
  if (lane == 0) wred[wave] = acc2;
  __syncthreads();
  if (tid == 0) {
    float fm2 = wred[0] + wred[1] + wred[2] + wred[3];
    float f1 = bias[0] + fm1db[0];
#pragma unroll
    for (int j = 0; j < F_FIELDS; ++j) f1 += sc1[j];
    for (int k = 0; k < ND; ++k) f1 += Xd[b * ND + k] * fm1dW[k];
    fm12[b] = f1 + fm2;
  }
}

// ---- GEMM1 fused-dense: Y1part = (A + relu(Xd@dW^T+db)) @ W1^T -------------
// 64x256 tile, depth-2 3-buffer pipeline, split-K 8 (plane = id&7 per XCD).
// D-tile generated in-kernel per K-step via 2x mfma 16x16x32 on augmented
// (K=32 zero-padded) Xd/dW rows; bias via augmented k=13 column of 1.0.
__global__ __launch_bounds__(256) void k_gemm1(
    const unsigned short* __restrict__ A, const unsigned short* __restrict__ B,
    const unsigned short* __restrict__ dWb, const float* __restrict__ Xd,
    float* __restrict__ C) {
  __shared__ __align__(16) unsigned short sA[3][64 * 32];    // 12 KB
  __shared__ __align__(16) unsigned short sB[3][256 * 32];   // 48 KB
  __shared__ __align__(16) unsigned short sWd[3][1024];      // 6 KB (32e x 32k)
  __shared__ __align__(16) unsigned short sD[64 * 32];       // 4 KB
  __shared__ __align__(16) unsigned short sXd[64 * 32];      // 4 KB (augmented)
  const int tid = threadIdx.x;
  const int lane = tid & 63, w = tid >> 6;
  const int id = blockIdx.x;
  const int p = id & 7, mt = id >> 3;
  const int m0 = mt * 64;
  const int s0 = (338 * p) >> 3, s1 = (338 * (p + 1)) >> 3;
  C += (size_t)p * ((size_t)BS * H1_DIM);

  // stage augmented Xd rows (once): [s][0..12]=xd, [13]=1.0, [14..31]=0
  if (tid < 64) {
    const float* xr = Xd + (size_t)(m0 + tid) * ND;
    unsigned short row[32];
#pragma unroll
    for (int k = 0; k < 13; ++k) row[k] = f2bf(xr[k]);
    row[13] = 0x3F80;                          // bf16(1.0)
#pragma unroll
    for (int k = 14; k < 32; ++k) row[k] = 0;
#pragma unroll
    for (int k = 0; k < 32; ++k) sXd[tid * 32 + k] = row[k];
  }
  __syncthreads();

  const int q = tid & 3, rr = tid >> 2;       // rr 0..63
  const unsigned short* gA  = A + (size_t)(m0 + rr) * DNN_IN + q * 8;
  const unsigned short* gB0 = B + (size_t)rr * DNN_IN + q * 8;
  const int fr = lane & 15, fk = lane >> 4;
  const int oA = fr * 32 + fk * 8;
  const int oB = (w * 64 + fr) * 32 + fk * 8;

  // D-gen frags: this wave owns m-stripe w (rows w*16..w*16+15)
  const bf16x8 avd = *(const bf16x8*)&sXd[(w * 16 + fr) * 32 + fk * 8];
  const int oW0 = fr * 32 + fk * 8;            // e-col fr
  const int oW1 = (16 + fr) * 32 + fk * 8;     // e-col 16+fr
  const int drow = w * 16 + fk * 4;            // base output row for this lane

  f32x4 acc[4][4] = {};
  const f32x4 zf = {0.f, 0.f, 0.f, 0.f};

#define STAGE1(ks, bi) do { const int ko_ = (ks) * 32;                      \
    gload16(gA + ko_, &sA[bi][tid * 8]);                                    \
    gload16(gB0 + ko_, &sB[bi][tid * 8]);                                   \
    gload16(gB0 + (size_t)64 * DNN_IN + ko_, &sB[bi][2048 + tid * 8]);      \
    gload16(gB0 + (size_t)128 * DNN_IN + ko_, &sB[bi][4096 + tid * 8]);     \
    gload16(gB0 + (size_t)192 * DNN_IN + ko_, &sB[bi][6144 + tid * 8]);     \
    gload16(dWb + (size_t)ko_ * 32 + (size_t)lane * 8, &sWd[bi][lane * 8]); \
    gload16(dWb + (size_t)ko_ * 32 + 512 + (size_t)lane * 8,                \
            &sWd[bi][512 + lane * 8]); } while (0)

  STAGE1(s0, 0);
  if (s0 + 1 < s1) STAGE1(s0 + 1, 1);
  if (s0 + 2 < s1) STAGE1(s0 + 2, 2);

  int bi = 0;
  for (int ks = s0; ks < s1; ++ks) {
    if (ks + 2 < s1)      asm volatile("s_waitcnt vmcnt(14)" ::: "memory");
    else if (ks + 1 < s1) asm volatile("s_waitcnt vmcnt(7)" ::: "memory");
    else                  asm volatile("s_waitcnt vmcnt(0)" ::: "memory");
    __builtin_amdgcn_sched_barrier(0);
    __builtin_amdgcn_s_barrier();             // bar1: buf bi staged
    bf16x8 bw0 = *(const bf16x8*)&sWd[bi][oW0];
    bf16x8 bw1 = *(const bf16x8*)&sWd[bi][oW1];
    bf16x8 av[4], bv[4];
#pragma unroll
    for (int mi = 0; mi < 4; ++mi) av[mi] = *(const bf16x8*)&sA[bi][oA + mi * 512];
#pragma unroll
    for (int ni = 0; ni < 4; ++ni) bv[ni] = *(const bf16x8*)&sB[bi][oB + ni * 512];
    asm volatile("s_waitcnt lgkmcnt(0)" ::: "memory");
    __builtin_amdgcn_sched_barrier(0);
    // D-tile gen: 2x 16x16x32 (this wave's 16-row stripe x 32 e-cols)
    f32x4 d0 = __builtin_amdgcn_mfma_f32_16x16x32_bf16(avd, bw0, zf, 0, 0, 0);
    f32x4 d1 = __builtin_amdgcn_mfma_f32_16x16x32_bf16(avd, bw1, zf, 0, 0, 0);
    // main MFMA on A-tile
#pragma unroll
    for (int mi = 0; mi < 4; ++mi)
#pragma unroll
      for (int ni = 0; ni < 4; ++ni)
        acc[mi][ni] = __builtin_amdgcn_mfma_f32_16x16x32_bf16(
            av[mi], bv[ni], acc[mi][ni], 0, 0, 0);
    // relu + cvt + scatter D to sD (layout identical to sA: [row][32])
#pragma unroll
    for (int r = 0; r < 4; ++r) {
      sD[(drow + r) * 32 + fr]      = f2bf(fmaxf(d0[r], 0.f));
      sD[(drow + r) * 32 + 16 + fr] = f2bf(fmaxf(d1[r], 0.f));
    }
    asm volatile("s_waitcnt lgkmcnt(0)" ::: "memory");
    __builtin_amdgcn_sched_barrier(0);
    __builtin_amdgcn_s_barrier();             // bar2: sD ready, frags consumed
    if (ks + 3 < s1) STAGE1(ks + 3, bi);
    bf16x8 dv[4];
#pragma unroll
    for (int mi = 0; mi < 4; ++mi) dv[mi] = *(const bf16x8*)&sD[oA + mi * 512];
    asm volatile("s_waitcnt lgkmcnt(0)" ::: "memory");
    __builtin_amdgcn_sched_barrier(0);
#pragma unroll
    for (int mi = 0; mi < 4; ++mi)
#pragma unroll
      for (int ni = 0; ni < 4; ++ni)
        acc[mi][ni] = __builtin_amdgcn_mfma_f32_16x16x32_bf16(
            dv[mi], bv[ni], acc[mi][ni], 0, 0, 0);
    bi = bi + 1; if (bi == 3) bi = 0;
  }
#pragma unroll
  for (int mi = 0; mi < 4; ++mi)
#pragma unroll
    for (int ni = 0; ni < 4; ++ni)
#pragma unroll
      for (int r = 0; r < 4; ++r) {
        int row = m0 + mi * 16 + fk * 4 + r;
        int col = w * 64 + ni * 16 + fr;
        C[(size_t)row * H1_DIM + col] = acc[mi][ni][r];
      }
#undef STAGE1
}

// -------- stat1: reduce 8 planes + b1 -> Y1, per-group partial stats --------
__global__ __launch_bounds__(256) void k_stat1(
    const float* __restrict__ Yp, const float* __restrict__ b1,
    float* __restrict__ Y1, float* __restrict__ ps, float* __restrict__ pq) {
  const int g = blockIdx.x, n = threadIdx.x;   // 256 groups x 16 rows
  const size_t plane = (size_t)BS * H1_DIM;
  float s = 0.f, s2 = 0.f;
  float bn = b1[n];
  for (int bb = 0; bb < 16; ++bb) {
    size_t o = (size_t)(g * 16 + bb) * H1_DIM + n;
    float y = bn;
#pragma unroll
    for (int pp = 0; pp < NP1; ++pp) y += Yp[o + pp * plane];
    Y1[o] = y; s += y; s2 += y * y;
  }
  ps[g * H1_DIM + n] = s;
  pq[g * H1_DIM + n] = s2;
}

// ---- apply1: deterministic inline stats reduce + BN1 + relu -> H1 (bf16) ---
__global__ __launch_bounds__(256) void k_apply1(
    const float* __restrict__ Y1, const float* __restrict__ ps,
    const float* __restrict__ pq, const float* __restrict__ g1,
    const float* __restrict__ be1, unsigned short* __restrict__ H1b) {
  const int g = blockIdx.x, n = threadIdx.x;
  float s = 0.f, s2 = 0.f;
  for (int gg = 0; gg < 256; ++gg) {           // fixed order -> deterministic
    s += ps[gg * H1_DIM + n];
    s2 += pq[gg * H1_DIM + n];
  }
  float m = s * (1.f / BS);
  float v = s2 * (1.f / BS) - m * m;
  float r = rsqrtf(v + 1e-5f);
  float ga = g1[n], bb_ = be1[n];
  for (int bb = 0; bb < 16; ++bb) {
    size_t o = (size_t)(g * 16 + bb) * H1_DIM + n;
    float h = (Y1[o] - m) * r * ga + bb_;
    H1b[o] = f2bf(fmaxf(h, 0.f));
  }
}

// -------- GEMM2 (32 blocks) + bias + per-block partial column stats ---------
__global__ __launch_bounds__(256) void k_gemm2(
    const unsigned short* __restrict__ A, const unsigned short* __restrict__ B,
    const float* __restrict__ b2, float* __restrict__ Y2,
    float* __restrict__ ps, float* __restrict__ pq) {
  __shared__ __align__(16) unsigned short sA[2][128 * 32];
  __shared__ __align__(16) unsigned short sB[2][128 * 32];
  __shared__ float redS[8][H2_DIM];
  __shared__ float redQ[8][H2_DIM];
  const int tid = threadIdx.x;
  const int lane = tid & 63, wave = tid >> 6;
  const int m0 = blockIdx.x * 128;

  const int q = tid & 3, rr = tid >> 2;        // rr 0..63
  const unsigned short* gA0 = A + (size_t)(m0 + rr) * H1_DIM + q * 8;
  const unsigned short* gA1 = gA0 + (size_t)64 * H1_DIM;
  const unsigned short* gB0 = B + (size_t)rr * H1_DIM + q * 8;
  const unsigned short* gB1 = gB0 + (size_t)64 * H1_DIM;
  const int lo = wave * 512;

  const int wr = wave >> 1, wc = wave & 1;
  const int fr = lane & 15, fk = lane >> 4;
  const int oA = (wr * 64 + fr) * 32 + fk * 8;
  const int oB = (wc * 64 + fr) * 32 + fk * 8;

  f32x4 acc[4][4] = {};
  {
    gload16(gA0, &sA[0][lo]);
    gload16(gA1, &sA[0][2048 + lo]);
    gload16(gB0, &sB[0][lo]);
    gload16(gB1, &sB[0][2048 + lo]);
  }
  for (int ks = 0; ks < 8; ++ks) {
    const int cur = ks & 1;
    if (ks + 1 < 8) {
      const int ko = (ks + 1) * 32;
      gload16(gA0 + ko, &sA[cur ^ 1][lo]);
      gload16(gA1 + ko, &sA[cur ^ 1][2048 + lo]);
      gload16(gB0 + ko, &sB[cur ^ 1][lo]);
      gload16(gB1 + ko, &sB[cur ^ 1][2048 + lo]);
      asm volatile("s_waitcnt vmcnt(4)" ::: "memory");
    } else {
      asm volatile("s_waitcnt vmcnt(0)" ::: "memory");
    }
    __builtin_amdgcn_sched_barrier(0);
    __builtin_amdgcn_s_barrier();
    bf16x8 av[4], bv[4];
#pragma unroll
    for (int mi = 0; mi < 4; ++mi) av[mi] = *(const bf16x8*)&sA[cur][oA + mi * 512];
#pragma unroll
    for (int ni = 0; ni < 4; ++ni) bv[ni] = *(const bf16x8*)&sB[cur][oB + ni * 512];
    asm volatile("s_waitcnt lgkmcnt(0)" ::: "memory");
    __builtin_amdgcn_sched_barrier(0);
    __builtin_amdgcn_s_barrier();
#pragma unroll
    for (int mi = 0; mi < 4; ++mi)
#pragma unroll
      for (int ni = 0; ni < 4; ++ni)
        acc[mi][ni] = __builtin_amdgcn_mfma_f32_16x16x32_bf16(
            av[mi], bv[ni], acc[mi][ni], 0, 0, 0);
  }
  // epilogue: bias, store Y2, per-column partial stats over this block's rows
  float sc[4] = {0.f, 0.f, 0.f, 0.f}, sq[4] = {0.f, 0.f, 0.f, 0.f};
#pragma unroll
  for (int ni = 0; ni < 4; ++ni) {
    int col = wc * 64 + ni * 16 + fr;
    float bcol = b2[col];
#pragma unroll
    for (int mi = 0; mi < 4; ++mi)
#pragma unroll
      for (int r = 0; r < 4; ++r) {
        int row = m0 + wr * 64 + mi * 16 + fk * 4 + r;
        float y = acc[mi][ni][r] + bcol;
        Y2[(size_t)row * H2_DIM + col] = y;
        sc[ni] += y; sq[ni] += y * y;
      }
  }
  const int slot = wr * 4 + fk;
#pragma unroll
  for (int ni = 0; ni < 4; ++ni) {
    int col = wc * 64 + ni * 16 + fr;
    redS[slot][col] = sc[ni];
    redQ[slot][col] = sq[ni];
  }
  __syncthreads();
  if (tid < H2_DIM) {
    float s = 0.f, s2 = 0.f;
#pragma unroll
    for (int sl = 0; sl < 8; ++sl) { s += redS[sl][tid]; s2 += redQ[sl][tid]; }
    ps[blockIdx.x * H2_DIM + tid] = s;
    pq[blockIdx.x * H2_DIM + tid] = s2;
  }
}

// -- final: deterministic stats reduce + BN2 + relu + Wout dot + sigmoid -----
__global__ __launch_bounds__(256) void k_final(
    const float* __restrict__ Y2, const float* __restrict__ ps,
    const float* __restrict__ pq, const float* __restrict__ g2,
    const float* __restrict__ be2, const float* __restrict__ Wout,
    const float* __restrict__ bout, const float* __restrict__ fm12,
    float* __restrict__ out) {
  const int tid = threadIdx.x, wave = tid >> 6, lane = tid & 63;
  __shared__ float sm[H2_DIM], sr[H2_DIM], sg[H2_DIM], sbe[H2_DIM], sw[H2_DIM];
  if (tid < H2_DIM) {
    float s = 0.f, s2 = 0.f;
    for (int g = 0; g < 32; ++g) {             // fixed order -> deterministic
      s += ps[g * H2_DIM + tid];
      s2 += pq[g * H2_DIM + tid];
    }
    float m = s * (1.f / BS);
    float v = s2 * (1.f / BS) - m * m;
    sm[tid] = m; sr[tid] = rsqrtf(v + 1e-5f);
    sg[tid] = g2[tid]; sbe[tid] = be2[tid]; sw[tid] = Wout[tid];
  }
  __syncthreads();
  const float bo = bout[0];
  for (int ii = 0; ii < 16; ++ii) {
    int s = blockIdx.x * 64 + wave * 16 + ii;
    float acc = 0.f;
#pragma unroll
    for (int nn = 0; nn < 2; ++nn) {
      int n = lane + nn * 64;
      float y = Y2[(size_t)s * H2_DIM + n];
      float h = (y - sm[n]) * sr[n] * sg[n] + sbe[n];
      acc += fmaxf(h, 0.f) * sw[n];
    }
#pragma unroll
    for (int off = 32; off; off >>= 1) acc += __shfl_down(acc, off);
    if (lane == 0) {
      float logit = fm12[s] + acc + bo;
      out[s] = 1.f / (1.f + expf(-logit));
    }
  }
}

extern "C" void kernel_launch(void* const* d_in, const int* in_sizes, int n_in,
                              void* d_out, int out_size, void* d_ws, size_t ws_size,
                              hipStream_t stream) {
  const int*   Xs     = (const int*)d_in[0];
  const float* Xd     = (const float*)d_in[1];
  const float* fm1e   = (const float*)d_in[2];
  const float* bias   = (const float*)d_in[3];
  const float* fm1dW  = (const float*)d_in[4];
  const float* fm1db  = (const float*)d_in[5];
  const float* emb    = (const float*)d_in[6];
  const float* dW     = (const float*)d_in[7];
  const float* db_    = (const float*)d_in[8];
  const float* W1     = (const float*)d_in[9];
  const float* b1     = (const float*)d_in[10];
  const float* g1     = (const float*)d_in[11];
  const float* be1    = (const float*)d_in[12];
  const float* W2     = (const float*)d_in[13];
  const float* b2     = (const float*)d_in[14];
  const float* g2     = (const float*)d_in[15];
  const float* be2    = (const float*)d_in[16];
  const float* Wout   = (const float*)d_in[17];
  const float* bout   = (const float*)d_in[18];
  float* out = (float*)d_out;

  char* w = (char*)d_ws;
  unsigned short* Dnn = (unsigned short*)w; w += (size_t)BS * DNN_IN * 2;      // 88.6 MB
  unsigned short* W1b = (unsigned short*)w; w += (size_t)H1_DIM * DNN_IN * 2;  // 5.5 MB
  unsigned short* W2b = (unsigned short*)w; w += (size_t)H2_DIM * H1_DIM * 2;
  unsigned short* dWb = (unsigned short*)w; w += (size_t)DNN_IN * 32 * 2;      // 692 KB
  float* fm12 = (float*)w;  w += (size_t)BS * 4;
  float* Ypart = (float*)w; w += (size_t)NP1 * BS * H1_DIM * 4;                // 33.6 MB
  float* Y1 = (float*)w;    w += (size_t)BS * H1_DIM * 4;
  unsigned short* H1b = (unsigned short*)w; w += (size_t)BS * H1_DIM * 2;
  float* Y2 = (float*)w;    w += (size_t)BS * H2_DIM * 4;
  float* ps1 = (float*)w;   w += 256 * H1_DIM * 4;
  float* pq1 = (float*)w;   w += 256 * H1_DIM * 4;
  float* ps2 = (float*)w;   w += 32 * H2_DIM * 4;
  float* pq2 = (float*)w;   w += 32 * H2_DIM * 4;

  k_gather<<<BS, 256, 0, stream>>>(Xs, emb, fm1e, bias, fm1dW, fm1db, Xd,
                                   W1, W2, dW, db_, W1b, W2b, dWb, Dnn, fm12);
  k_gemm1<<<64 * NP1, 256, 0, stream>>>(Dnn, W1b, dWb, Xd, Ypart);
  k_stat1<<<256, 256, 0, stream>>>(Ypart, b1, Y1, ps1, pq1);
  k_apply1<<<256, 256, 0, stream>>>(Y1, ps1, pq1, g1, be1, H1b);
  k_gemm2<<<32, 256, 0, stream>>>(H1b, W2b, b2, Y2, ps2, pq2);
  k_final<<<BS / 64, 256, 0, stream>>>(Y2, ps2, pq2, g2, be2, Wout, bout, fm12, out);
}

// Round 7
// 183.698 us; speedup vs baseline: 2.3334x; 1.0187x over previous
//
#include <hip/hip_runtime.h>

typedef __bf16 bf16x8 __attribute__((ext_vector_type(8)));
typedef float f32x4 __attribute__((ext_vector_type(4)));

#define F_FIELDS 26
#define V_FIELD  8000
#define V_TOT    208000
#define D_EMBD   16
#define DNN_IN   10816   // 26*26*16
#define BS       4096
#define ND       13
#define H1_DIM   256
#define H2_DIM   128
#define NP1      8       // gemm1 split-K planes

__device__ __forceinline__ unsigned short f2bf(float f) {
  unsigned u = __float_as_uint(f);
  u += 0x7fffu + ((u >> 16) & 1u);      // round-to-nearest-even
  return (unsigned short)(u >> 16);
}
__device__ __forceinline__ float bf2f(unsigned short h) {
  return __uint_as_float(((unsigned)h) << 16);
}
__device__ __forceinline__ float bflo(unsigned u) { return __uint_as_float(u << 16); }
__device__ __forceinline__ float bfhi(unsigned u) { return __uint_as_float(u & 0xffff0000u); }
__device__ __forceinline__ unsigned packbf(float a, float b) {
  return (unsigned)f2bf(a) | ((unsigned)f2bf(b) << 16);
}

__device__ __forceinline__ void gload16(const void* g, void* l) {
  __builtin_amdgcn_global_load_lds(
      (const __attribute__((address_space(1))) unsigned int*)g,
      (__attribute__((address_space(3))) unsigned int*)l, 16, 0, 0);
}

__device__ __forceinline__ float dot8bf(uint4 a, uint4 b) {
  const unsigned* pa = (const unsigned*)&a;
  const unsigned* pb = (const unsigned*)&b;
  float s = 0.f;
#pragma unroll
  for (int k = 0; k < 4; ++k)
    s += bflo(pa[k]) * bflo(pb[k]) + bfhi(pa[k]) * bfhi(pb[k]);
  return s;
}

// ------- gather: A tensor + fm1 + fm2 + W1/W2/dense-W bf16 conversion -------
// block = one sample. A[b,i,j,:] = emb[i, X[b,j], :]; 676 rows of 16 floats.
__global__ __launch_bounds__(256) void k_gather(
    const int* __restrict__ Xs, const float* __restrict__ emb,
    const float* __restrict__ fm1_emb, const float* __restrict__ bias,
    const float* __restrict__ fm1dW, const float* __restrict__ fm1db,
    const float* __restrict__ Xd,
    const float* __restrict__ W1, const float* __restrict__ W2,
    const float* __restrict__ dW, const float* __restrict__ db_,
    unsigned short* __restrict__ W1b, unsigned short* __restrict__ W2b,
    unsigned short* __restrict__ dWb,
    unsigned short* __restrict__ Abf, float* __restrict__ fm12) {
  const int b = blockIdx.x;
  const int tid = threadIdx.x;
  const int lane = tid & 63, wave = tid >> 6;
  __shared__ int   sidx[F_FIELDS];
  __shared__ float sc1[F_FIELDS];
  __shared__ __align__(16) unsigned short As[676 * 16];  // bf16, 21.6 KB
  __shared__ float wred[4];

  if (tid < F_FIELDS) {
    int v = Xs[b * F_FIELDS + tid] + tid * V_FIELD;
    sidx[tid] = v;
    sc1[tid] = fm1_emb[v];
  }
  __syncthreads();

  const int q = tid & 3, rbase = tid >> 2;   // 4 lanes per row (float4 each)
  float4 vv[11];
#pragma unroll
  for (int it = 0; it < 11; ++it) {          // issue all gathers first (MLP)
    int r = rbase + it * 64;
    if (r < 676) {
      int i = r / 26, j = r - i * 26;
      const float* src = emb + ((size_t)i * V_TOT + sidx[j]) * D_EMBD + q * 4;
      vv[it] = *(const float4*)src;
    }
  }
  // W1/W2 -> bf16 conversion: independent work overlapping gather latency
  const int n1 = H1_DIM * DNN_IN, n2 = H2_DIM * H1_DIM;
  for (int t = b * 256 + tid; t < n1 + n2; t += BS * 256) {
    if (t < n1) W1b[t] = f2bf(W1[t]);
    else        W2b[t - n1] = f2bf(W2[t - n1]);
  }
  // dense-W augmented bf16 table (K=32): [0..12]=w, [13]=db, [14..31]=0
  for (int e = b * 256 + tid; e < DNN_IN; e += BS * 256) {
    unsigned short row[32];
#pragma unroll
    for (int k = 0; k < 13; ++k) row[k] = f2bf(dW[e * 13 + k]);
    row[13] = f2bf(db_[e]);
#pragma unroll
    for (int k = 14; k < 32; ++k) row[k] = 0;
#pragma unroll
    for (int k = 0; k < 32; ++k) dWb[e * 32 + k] = row[k];
  }
#pragma unroll
  for (int it = 0; it < 11; ++it) {
    int r = rbase + it * 64;
    if (r < 676) {
      ushort4 u;
      u.x = f2bf(vv[it].x); u.y = f2bf(vv[it].y);
      u.z = f2bf(vv[it].z); u.w = f2bf(vv[it].w);
      *(ushort4*)&As[r * 16 + q * 4] = u;
      *(ushort4*)&Abf[(size_t)b * DNN_IN + r * 16 + q * 4] = u;
    }
  }
  __syncthreads();

  // fm2 = sum_{i<j} dot(A[b,i,j,:], A[b,j,i,:]) ; 325 pairs (bf16 products)
  float acc2 = 0.f;
  for (int p = tid; p < 325; p += 256) {
    float disc = sqrtf((float)(2601 - 8 * p));   // exact for perfect squares
    int i = (int)((51.f - disc) * 0.5f);
    int cum = 25 * i - ((i * (i - 1)) >> 1);
    int j = i + 1 + (p - cum);
    const unsigned short* r1 = &As[(i * 26 + j) * 16];
    const unsigned short* r2 = &As[(j * 26 + i) * 16];
    acc2 += dot8bf(*(const uint4*)r1, *(const uint4*)r2);
    acc2 += dot8bf(*(const uint4*)(r1 + 8), *(const uint4*)(r2 + 8));
  }
#pragma unroll
  for (int off = 32; off; off >>= 1) acc2 += __shfl_down(acc2, off);
  if (lane == 0) wred[wave] = acc2;
  __syncthreads();
  if (tid == 0) {
    float fm2 = wred[0] + wred[1] + wred[2] + wred[3];
    float f1 = bias[0] + fm1db[0];
#pragma unroll
    for (int j = 0; j < F_FIELDS; ++j) f1 += sc1[j];
    for (int k = 0; k < ND; ++k) f1 += Xd[b * ND + k] * fm1dW[k];
    fm12[b] = f1 + fm2;
  }
}

// ---- GEMM1 fused-dense: Y1part = (A + relu(Xd@dW^T+db)) @ W1^T -------------
// 64x256 tile, depth-2 3-buffer pipeline, split-K 8 (plane = id&7 per XCD).
// E-merge: per K-step, D-tile via 2x swapped-operand mfma 16x16x32
// (C layout -> lane holds 4 consecutive e for one sample -> b64 writes),
// E = bf16(A + relu(D)) built in sD, then a SINGLE set of 16 MFMA on E.
__global__ __launch_bounds__(256) void k_gemm1(
    const unsigned short* __restrict__ A, const unsigned short* __restrict__ B,
    const unsigned short* __restrict__ dWb, const float* __restrict__ Xd,
    unsigned short* __restrict__ C) {
  __shared__ __align__(16) unsigned short sA[3][64 * 32];    // 12 KB
  __shared__ __align__(16) unsigned short sB[3][256 * 32];   // 48 KB
  __shared__ __align__(16) unsigned short sWd[3][1024];      // 6 KB (32e x 32k)
  __shared__ __align__(16) unsigned short sD[64 * 32];       // 4 KB (E-tile)
  __shared__ __align__(16) unsigned short sXd[64 * 32];      // 4 KB (augmented)
  const int tid = threadIdx.x;
  const int lane = tid & 63, w = tid >> 6;
  const int id = blockIdx.x;
  const int p = id & 7, mt = id >> 3;
  const int m0 = mt * 64;
  const int s0 = (338 * p) >> 3, s1 = (338 * (p + 1)) >> 3;
  C += (size_t)p * ((size_t)BS * H1_DIM);

  // stage augmented Xd rows (once): [s][0..12]=xd, [13]=1.0, [14..31]=0
  if (tid < 64) {
    const float* xr = Xd + (size_t)(m0 + tid) * ND;
    unsigned short row[32];
#pragma unroll
    for (int k = 0; k < 13; ++k) row[k] = f2bf(xr[k]);
    row[13] = 0x3F80;                          // bf16(1.0)
#pragma unroll
    for (int k = 14; k < 32; ++k) row[k] = 0;
#pragma unroll
    for (int k = 0; k < 32; ++k) sXd[tid * 32 + k] = row[k];
  }
  __syncthreads();

  const int q = tid & 3, rr = tid >> 2;       // rr 0..63
  const unsigned short* gA  = A + (size_t)(m0 + rr) * DNN_IN + q * 8;
  const unsigned short* gB0 = B + (size_t)rr * DNN_IN + q * 8;
  const int fr = lane & 15, fk = lane >> 4;
  const int oA = fr * 32 + fk * 8;             // frag base (rows=samples)
  const int oB = (w * 64 + fr) * 32 + fk * 8;

  // D-gen (swapped operands): A-op = dW_aug rows, B-op = Xd_aug samples.
  // B-frag: lane holds Xd_aug[sample = w*16+fr, k = fk*8..]
  const bf16x8 bvd = *(const bf16x8*)&sXd[(w * 16 + fr) * 32 + fk * 8];
  const int erow = (w * 16 + fr) * 32;         // sD row base for this lane
  const int ecol = fk * 4;                     // 4 consecutive e per mfma reg

  f32x4 acc[4][4] = {};
  const f32x4 zf = {0.f, 0.f, 0.f, 0.f};

#define STAGE1(ks, bi) do { const int ko_ = (ks) * 32;                      \
    gload16(gA + ko_, &sA[bi][tid * 8]);                                    \
    gload16(gB0 + ko_, &sB[bi][tid * 8]);                                   \
    gload16(gB0 + (size_t)64 * DNN_IN + ko_, &sB[bi][2048 + tid * 8]);      \
    gload16(gB0 + (size_t)128 * DNN_IN + ko_, &sB[bi][4096 + tid * 8]);     \
    gload16(gB0 + (size_t)192 * DNN_IN + ko_, &sB[bi][6144 + tid * 8]);     \
    gload16(dWb + (size_t)ko_ * 32 + (size_t)lane * 8, &sWd[bi][lane * 8]); \
    gload16(dWb + (size_t)ko_ * 32 + 512 + (size_t)lane * 8,                \
            &sWd[bi][512 + lane * 8]); } while (0)

  STAGE1(s0, 0);
  if (s0 + 1 < s1) STAGE1(s0 + 1, 1);
  if (s0 + 2 < s1) STAGE1(s0 + 2, 2);

  int bi = 0;
  for (int ks = s0; ks < s1; ++ks) {
    if (ks + 2 < s1)      asm volatile("s_waitcnt vmcnt(14)" ::: "memory");
    else if (ks + 1 < s1) asm volatile("s_waitcnt vmcnt(7)" ::: "memory");
    else                  asm volatile("s_waitcnt vmcnt(0)" ::: "memory");
    __builtin_amdgcn_sched_barrier(0);
    __builtin_amdgcn_s_barrier();             // bar1: buf bi staged
    // A-op frags for D-gen: dW_aug[e = fr (+16), k = fk*8..]
    bf16x8 aw0 = *(const bf16x8*)&sWd[bi][fr * 32 + fk * 8];
    bf16x8 aw1 = *(const bf16x8*)&sWd[bi][(16 + fr) * 32 + fk * 8];
    bf16x8 bv[4];
#pragma unroll
    for (int ni = 0; ni < 4; ++ni) bv[ni] = *(const bf16x8*)&sB[bi][oB + ni * 512];
    // this lane's A values at its 8 E positions (sample w*16+fr, e=ecol..+3, +16)
    uint2 a0 = *(const uint2*)&sA[bi][erow + ecol];
    uint2 a1 = *(const uint2*)&sA[bi][erow + 16 + ecol];
    asm volatile("s_waitcnt lgkmcnt(0)" ::: "memory");
    __builtin_amdgcn_sched_barrier(0);
    // D-gen: C[m=e, n=sample] -> lane reg r holds (e=ecol+r, sample=w*16+fr)
    f32x4 d0 = __builtin_amdgcn_mfma_f32_16x16x32_bf16(aw0, bvd, zf, 0, 0, 0);
    f32x4 d1 = __builtin_amdgcn_mfma_f32_16x16x32_bf16(aw1, bvd, zf, 0, 0, 0);
    // E = bf16(A + relu(D)); two b64 writes (4 consecutive e each)
    uint2 e0, e1;
    e0.x = packbf(bflo(a0.x) + fmaxf(d0[0], 0.f), bfhi(a0.x) + fmaxf(d0[1], 0.f));
    e0.y = packbf(bflo(a0.y) + fmaxf(d0[2], 0.f), bfhi(a0.y) + fmaxf(d0[3], 0.f));
    e1.x = packbf(bflo(a1.x) + fmaxf(d1[0], 0.f), bfhi(a1.x) + fmaxf(d1[1], 0.f));
    e1.y = packbf(bflo(a1.y) + fmaxf(d1[2], 0.f), bfhi(a1.y) + fmaxf(d1[3], 0.f));
    *(uint2*)&sD[erow + ecol] = e0;
    *(uint2*)&sD[erow + 16 + ecol] = e1;
    asm volatile("s_waitcnt lgkmcnt(0)" ::: "memory");
    __builtin_amdgcn_sched_barrier(0);
    __builtin_amdgcn_s_barrier();             // bar2: sD(E) complete
    if (ks + 3 < s1) STAGE1(ks + 3, bi);
    bf16x8 ev[4];
#pragma unroll
    for (int mi = 0; mi < 4; ++mi) ev[mi] = *(const bf16x8*)&sD[oA + mi * 512];
    asm volatile("s_waitcnt lgkmcnt(0)" ::: "memory");
    __builtin_amdgcn_sched_barrier(0);
#pragma unroll
    for (int mi = 0; mi < 4; ++mi)
#pragma unroll
      for (int ni = 0; ni < 4; ++ni)
        acc[mi][ni] = __builtin_amdgcn_mfma_f32_16x16x32_bf16(
            ev[mi], bv[ni], acc[mi][ni], 0, 0, 0);
    bi = bi + 1; if (bi == 3) bi = 0;
  }
#pragma unroll
  for (int mi = 0; mi < 4; ++mi)
#pragma unroll
    for (int ni = 0; ni < 4; ++ni)
#pragma unroll
      for (int r = 0; r < 4; ++r) {
        int row = m0 + mi * 16 + fk * 4 + r;
        int col = w * 64 + ni * 16 + fr;
        C[(size_t)row * H1_DIM + col] = f2bf(acc[mi][ni][r]);
      }
#undef STAGE1
}

// -------- stat1: reduce 8 bf16 planes + b1 -> Y1, per-group partials --------
__global__ __launch_bounds__(256) void k_stat1(
    const unsigned short* __restrict__ Yp, const float* __restrict__ b1,
    float* __restrict__ Y1, float* __restrict__ ps, float* __restrict__ pq) {
  const int g = blockIdx.x, n = threadIdx.x;   // 256 groups x 16 rows
  const size_t plane = (size_t)BS * H1_DIM;
  float s = 0.f, s2 = 0.f;
  float bn = b1[n];
  for (int bb = 0; bb < 16; ++bb) {
    size_t o = (size_t)(g * 16 + bb) * H1_DIM + n;
    float y = bn;
#pragma unroll
    for (int pp = 0; pp < NP1; ++pp) y += bf2f(Yp[o + pp * plane]);
    Y1[o] = y; s += y; s2 += y * y;
  }
  ps[g * H1_DIM + n] = s;
  pq[g * H1_DIM + n] = s2;
}

// ---- apply1: deterministic inline stats reduce + BN1 + relu -> H1 (bf16) ---
__global__ __launch_bounds__(256) void k_apply1(
    const float* __restrict__ Y1, const float* __restrict__ ps,
    const float* __restrict__ pq, const float* __restrict__ g1,
    const float* __restrict__ be1, unsigned short* __restrict__ H1b) {
  const int g = blockIdx.x, n = threadIdx.x;
  float s = 0.f, s2 = 0.f;
  for (int gg = 0; gg < 256; ++gg) {           // fixed order -> deterministic
    s += ps[gg * H1_DIM + n];
    s2 += pq[gg * H1_DIM + n];
  }
  float m = s * (1.f / BS);
  float v = s2 * (1.f / BS) - m * m;
  float r = rsqrtf(v + 1e-5f);
  float ga = g1[n], bb_ = be1[n];
  for (int bb = 0; bb < 16; ++bb) {
    size_t o = (size_t)(g * 16 + bb) * H1_DIM + n;
    float h = (Y1[o] - m) * r * ga + bb_;
    H1b[o] = f2bf(fmaxf(h, 0.f));
  }
}

// -------- GEMM2 (32 blocks) + bias + per-block partial column stats ---------
__global__ __launch_bounds__(256) void k_gemm2(
    const unsigned short* __restrict__ A, const unsigned short* __restrict__ B,
    const float* __restrict__ b2, float* __restrict__ Y2,
    float* __restrict__ ps, float* __restrict__ pq) {
  __shared__ __align__(16) unsigned short sA[2][128 * 32];
  __shared__ __align__(16) unsigned short sB[2][128 * 32];
  __shared__ float redS[8][H2_DIM];
  __shared__ float redQ[8][H2_DIM];
  const int tid = threadIdx.x;
  const int lane = tid & 63, wave = tid >> 6;
  const int m0 = blockIdx.x * 128;

  const int q = tid & 3, rr = tid >> 2;        // rr 0..63
  const unsigned short* gA0 = A + (size_t)(m0 + rr) * H1_DIM + q * 8;
  const unsigned short* gA1 = gA0 + (size_t)64 * H1_DIM;
  const unsigned short* gB0 = B + (size_t)rr * H1_DIM + q * 8;
  const unsigned short* gB1 = gB0 + (size_t)64 * H1_DIM;
  const int lo = wave * 512;

  const int wr = wave >> 1, wc = wave & 1;
  const int fr = lane & 15, fk = lane >> 4;
  const int oA = (wr * 64 + fr) * 32 + fk * 8;
  const int oB = (wc * 64 + fr) * 32 + fk * 8;

  f32x4 acc[4][4] = {};
  {
    gload16(gA0, &sA[0][lo]);
    gload16(gA1, &sA[0][2048 + lo]);
    gload16(gB0, &sB[0][lo]);
    gload16(gB1, &sB[0][2048 + lo]);
  }
  for (int ks = 0; ks < 8; ++ks) {
    const int cur = ks & 1;
    if (ks + 1 < 8) {
      const int ko = (ks + 1) * 32;
      gload16(gA0 + ko, &sA[cur ^ 1][lo]);
      gload16(gA1 + ko, &sA[cur ^ 1][2048 + lo]);
      gload16(gB0 + ko, &sB[cur ^ 1][lo]);
      gload16(gB1 + ko, &sB[cur ^ 1][2048 + lo]);
      asm volatile("s_waitcnt vmcnt(4)" ::: "memory");
    } else {
      asm volatile("s_waitcnt vmcnt(0)" ::: "memory");
    }
    __builtin_amdgcn_sched_barrier(0);
    __builtin_amdgcn_s_barrier();
    bf16x8 av[4], bv[4];
#pragma unroll
    for (int mi = 0; mi < 4; ++mi) av[mi] = *(const bf16x8*)&sA[cur][oA + mi * 512];
#pragma unroll
    for (int ni = 0; ni < 4; ++ni) bv[ni] = *(const bf16x8*)&sB[cur][oB + ni * 512];
    asm volatile("s_waitcnt lgkmcnt(0)" ::: "memory");
    __builtin_amdgcn_sched_barrier(0);
    __builtin_amdgcn_s_barrier();
#pragma unroll
    for (int mi = 0; mi < 4; ++mi)
#pragma unroll
      for (int ni = 0; ni < 4; ++ni)
        acc[mi][ni] = __builtin_amdgcn_mfma_f32_16x16x32_bf16(
            av[mi], bv[ni], acc[mi][ni], 0, 0, 0);
  }
  // epilogue: bias, store Y2, per-column partial stats over this block's rows
  float sc[4] = {0.f, 0.f, 0.f, 0.f}, sq[4] = {0.f, 0.f, 0.f, 0.f};
#pragma unroll
  for (int ni = 0; ni < 4; ++ni) {
    int col = wc * 64 + ni * 16 + fr;
    float bcol = b2[col];
#pragma unroll
    for (int mi = 0; mi < 4; ++mi)
#pragma unroll
      for (int r = 0; r < 4; ++r) {
        int row = m0 + wr * 64 + mi * 16 + fk * 4 + r;
        float y = acc[mi][ni][r] + bcol;
        Y2[(size_t)row * H2_DIM + col] = y;
        sc[ni] += y; sq[ni] += y * y;
      }
  }
  const int slot = wr * 4 + fk;
#pragma unroll
  for (int ni = 0; ni < 4; ++ni) {
    int col = wc * 64 + ni * 16 + fr;
    redS[slot][col] = sc[ni];
    redQ[slot][col] = sq[ni];
  }
  __syncthreads();
  if (tid < H2_DIM) {
    float s = 0.f, s2 = 0.f;
#pragma unroll
    for (int sl = 0; sl < 8; ++sl) { s += redS[sl][tid]; s2 += redQ[sl][tid]; }
    ps[blockIdx.x * H2_DIM + tid] = s;
    pq[blockIdx.x * H2_DIM + tid] = s2;
  }
}

// -- final: deterministic stats reduce + BN2 + relu + Wout dot + sigmoid -----
__global__ __launch_bounds__(256) void k_final(
    const float* __restrict__ Y2, const float* __restrict__ ps,
    const float* __restrict__ pq, const float* __restrict__ g2,
    const float* __restrict__ be2, const float* __restrict__ Wout,
    const float* __restrict__ bout, const float* __restrict__ fm12,
    float* __restrict__ out) {
  const int tid = threadIdx.x, wave = tid >> 6, lane = tid & 63;
  __shared__ float sm[H2_DIM], sr[H2_DIM], sg[H2_DIM], sbe[H2_DIM], sw[H2_DIM];
  if (tid < H2_DIM) {
    float s = 0.f, s2 = 0.f;
    for (int g = 0; g < 32; ++g) {             // fixed order -> deterministic
      s += ps[g * H2_DIM + tid];
      s2 += pq[g * H2_DIM + tid];
    }
    float m = s * (1.f / BS);
    float v = s2 * (1.f / BS) - m * m;
    sm[tid] = m; sr[tid] = rsqrtf(v + 1e-5f);
    sg[tid] = g2[tid]; sbe[tid] = be2[tid]; sw[tid] = Wout[tid];
  }
  __syncthreads();
  const float bo = bout[0];
  for (int ii = 0; ii < 16; ++ii) {
    int s = blockIdx.x * 64 + wave * 16 + ii;
    float acc = 0.f;
#pragma unroll
    for (int nn = 0; nn < 2; ++nn) {
      int n = lane + nn * 64;
      float y = Y2[(size_t)s * H2_DIM + n];
      float h = (y - sm[n]) * sr[n] * sg[n] + sbe[n];
      acc += fmaxf(h, 0.f) * sw[n];
    }
#pragma unroll
    for (int off = 32; off; off >>= 1) acc += __shfl_down(acc, off);
    if (lane == 0) {
      float logit = fm12[s] + acc + bo;
      out[s] = 1.f / (1.f + expf(-logit));
    }
  }
}

extern "C" void kernel_launch(void* const* d_in, const int* in_sizes, int n_in,
                              void* d_out, int out_size, void* d_ws, size_t ws_size,
                              hipStream_t stream) {
  const int*   Xs     = (const int*)d_in[0];
  const float* Xd     = (const float*)d_in[1];
  const float* fm1e   = (const float*)d_in[2];
  const float* bias   = (const float*)d_in[3];
  const float* fm1dW  = (const float*)d_in[4];
  const float* fm1db  = (const float*)d_in[5];
  const float* emb    = (const float*)d_in[6];
  const float* dW     = (const float*)d_in[7];
  const float* db_    = (const float*)d_in[8];
  const float* W1     = (const float*)d_in[9];
  const float* b1     = (const float*)d_in[10];
  const float* g1     = (const float*)d_in[11];
  const float* be1    = (const float*)d_in[12];
  const float* W2     = (const float*)d_in[13];
  const float* b2     = (const float*)d_in[14];
  const float* g2     = (const float*)d_in[15];
  const float* be2    = (const float*)d_in[16];
  const float* Wout   = (const float*)d_in[17];
  const float* bout   = (const float*)d_in[18];
  float* out = (float*)d_out;

  char* w = (char*)d_ws;
  unsigned short* Dnn = (unsigned short*)w; w += (size_t)BS * DNN_IN * 2;      // 88.6 MB
  unsigned short* W1b = (unsigned short*)w; w += (size_t)H1_DIM * DNN_IN * 2;  // 5.5 MB
  unsigned short* W2b = (unsigned short*)w; w += (size_t)H2_DIM * H1_DIM * 2;
  unsigned short* dWb = (unsigned short*)w; w += (size_t)DNN_IN * 32 * 2;      // 692 KB
  float* fm12 = (float*)w;  w += (size_t)BS * 4;
  unsigned short* Ypart = (unsigned short*)w; w += (size_t)NP1 * BS * H1_DIM * 2; // 16.8 MB
  float* Y1 = (float*)w;    w += (size_t)BS * H1_DIM * 4;
  unsigned short* H1b = (unsigned short*)w; w += (size_t)BS * H1_DIM * 2;
  float* Y2 = (float*)w;    w += (size_t)BS * H2_DIM * 4;
  float* ps1 = (float*)w;   w += 256 * H1_DIM * 4;
  float* pq1 = (float*)w;   w += 256 * H1_DIM * 4;
  float* ps2 = (float*)w;   w += 32 * H2_DIM * 4;
  float* pq2 = (float*)w;   w += 32 * H2_DIM * 4;

  k_gather<<<BS, 256, 0, stream>>>(Xs, emb, fm1e, bias, fm1dW, fm1db, Xd,
                                   W1, W2, dW, db_, W1b, W2b, dWb, Dnn, fm12);
  k_gemm1<<<64 * NP1, 256, 0, stream>>>(Dnn, W1b, dWb, Xd, Ypart);
  k_stat1<<<256, 256, 0, stream>>>(Ypart, b1, Y1, ps1, pq1);
  k_apply1<<<256, 256, 0, stream>>>(Y1, ps1, pq1, g1, be1, H1b);
  k_gemm2<<<32, 256, 0, stream>>>(H1b, W2b, b2, Y2, ps2, pq2);
  k_final<<<BS / 64, 256, 0, stream>>>(Y2, ps2, pq2, g2, be2, Wout, bout, fm12, out);
}